// Round 6
// baseline (689.269 us; speedup 1.0000x reference)
//
#include <hip/hip_runtime.h>
#include <math.h>

// ---------------- problem constants ----------------
#define NTOK 4096      // B*T
#define DM   5120      // d_model
#define FD   384       // ffn_dim
#define NE   32        // routed experts

typedef float  f32x4  __attribute__((ext_vector_type(4)));
typedef __bf16 bf16x8 __attribute__((ext_vector_type(8)));
typedef unsigned short us2 __attribute__((ext_vector_type(2)));
typedef unsigned short us4 __attribute__((ext_vector_type(4)));
typedef unsigned short us8 __attribute__((ext_vector_type(8)));

__device__ __forceinline__ unsigned short f2bf(float f) {
  unsigned int u = __float_as_uint(f);
  u += 0x7fffu + ((u >> 16) & 1u);     // RNE
  return (unsigned short)(u >> 16);
}

__device__ __forceinline__ float gelu_f(float v) {
  return 0.5f * v * (1.0f + erff(v * 0.70710678118654752f));  // exact erf gelu
}

__device__ __forceinline__ bf16x8 ldf(const unsigned short* p) {
  us4 lo = *(const us4*)p;
  us4 hi = *(const us4*)(p + 4);
  us8 v = {lo[0], lo[1], lo[2], lo[3], hi[0], hi[1], hi[2], hi[3]};
  return __builtin_bit_cast(bf16x8, v);
}

__device__ __forceinline__ f32x4 mfma16(bf16x8 a, bf16x8 b, f32x4 c) {
  return __builtin_amdgcn_mfma_f32_16x16x32_bf16(a, b, c, 0, 0, 0);
}

// XOR-swizzled LDS tile helpers (tile row stride = 64 bf16 = 128B; g = 16B group)
__device__ __forceinline__ bf16x8 fragld(const unsigned short* t, int row, int g) {
  return *(const bf16x8*)(t + row * 64 + ((g ^ (row & 7)) << 3));
}
__device__ __forceinline__ void fragst(unsigned short* t, int row, int g, us8 v) {
  *(us8*)(t + row * 64 + ((g ^ (row & 7)) << 3)) = v;
}

// ================= OLD-PATH ws layout (fallback; 15.3 MB) =================
#define OFF_LOGITS 0
#define OFF_COUNTS 524288
#define OFF_SEGC   524800
#define OFF_SEGB   525312
#define OFF_TABA   525824
#define OFF_TABR0  528896
#define OFF_TABR1  529920
#define OFF_TNS    530944
#define OFF_LISTS  531456
#define OFF_WLISTS 1580032
#define OFF_HBUF   2628608
#define WS_OLD     15260672UL

// ================= NEW-PATH ws layout =================
#define L_LOGITS 0UL
#define L_COUNTS 524288UL
#define L_HBASE  524544UL
#define L_TABA   524800UL
#define L_TABR0  527360UL
#define L_TABR1  528384UL
#define L_TNS    529408UL
#define L_LISTS  529536UL
#define L_WLIST  1578112UL
#define L_HBUF   2626688UL
#define L_XBF    15258752UL
#define L_W1T    57201792UL
#define L_W2ST   190895232UL
#define L_W2RT   198759552UL
#define WS_NEW   324588672UL

// ---------------- gate v3: fp64-accurate logits + x->bf16 fold ----------------
__global__ __launch_bounds__(256) void gate_v3(
    const float* __restrict__ x, const float* __restrict__ gw,
    const float* __restrict__ gb, float* __restrict__ logits,
    unsigned short* __restrict__ xbf)
{
  __shared__ __align__(16) char gsm[22656];
  float*  xs = (float*)gsm;              // [8][132] f32
  float*  gs = (float*)(gsm + 4224);     // [128][36] f32
  double* ps = (double*)(gsm + 4224);    // [8][8][32] f64, reused after K loop

  int tid = threadIdx.x;
  int t0 = blockIdx.x * 8;

  int col  = tid & 15;
  int row  = (tid >> 4) & 1;
  int part = tid >> 5;
  int e0 = col * 2;

  double a[4][2];
  #pragma unroll
  for (int i = 0; i < 4; ++i) { a[i][0] = 0.0; a[i][1] = 0.0; }

  int sx_r = tid >> 5;
  int sx_c = (tid & 31) * 4;
  const float* xg = x + (size_t)(t0 + sx_r) * DM + sx_c;
  unsigned short* xo = xbf + (size_t)(t0 + sx_r) * DM + sx_c;

  for (int k0 = 0; k0 < DM; k0 += 128) {
    float4 xv4 = *(const float4*)(xg + k0);
    *(float4*)&xs[sx_r * 132 + sx_c] = xv4;
    us4 hx = {f2bf(xv4.x), f2bf(xv4.y), f2bf(xv4.z), f2bf(xv4.w)};
    *(us4*)(xo + k0) = hx;
    #pragma unroll
    for (int p = 0; p < 4; ++p) {
      int idx = p * 256 + tid;
      int r = idx >> 3, q = (idx & 7) * 4;
      float4 g4 = *(const float4*)(gw + (size_t)(k0 + r) * NE + q);
      *(float4*)&gs[r * 36 + q] = g4;
    }
    __syncthreads();
    #pragma unroll
    for (int kk = 0; kk < 16; ++kk) {
      int k = part * 16 + kk;
      double g0 = (double)gs[k * 36 + e0];
      double g1 = (double)gs[k * 36 + e0 + 1];
      #pragma unroll
      for (int i = 0; i < 4; ++i) {
        double xv = (double)xs[(row * 4 + i) * 132 + k];
        a[i][0] = fma(xv, g0, a[i][0]);
        a[i][1] = fma(xv, g1, a[i][1]);
      }
    }
    __syncthreads();
  }

  #pragma unroll
  for (int i = 0; i < 4; ++i) {
    double2 v; v.x = a[i][0]; v.y = a[i][1];
    *(double2*)&ps[(size_t)part * 256 + (row * 4 + i) * 32 + e0] = v;
  }
  __syncthreads();
  {
    int t = tid >> 5, e = tid & 31;
    double s = 0.0;
    #pragma unroll
    for (int p = 0; p < 8; ++p) s += ps[(size_t)p * 256 + t * 32 + e];
    logits[(size_t)(t0 + t) * NE + e] = (float)s + gb[e];
  }
}

// ---------------- old gate (fallback path only) ----------------
__global__ __launch_bounds__(256) void gate_logits_kernel(
    const float* __restrict__ x, const float* __restrict__ gw,
    const float* __restrict__ gb, float* __restrict__ logits,
    unsigned short* __restrict__ xbf)
{
  __shared__ float xs[16][33];
  __shared__ float gs[32][33];
  int tid = threadIdx.x;
  int t0 = blockIdx.x * 16;
  int r = tid >> 4;
  int e0 = (tid & 15) * 2;
  double a0 = 0.0, a1 = 0.0;
  for (int k0 = 0; k0 < DM; k0 += 32) {
    {
      int rr = tid >> 4, cc = (tid & 15) * 2;
      const float* s = x + (size_t)(t0 + rr) * DM + k0 + cc;
      float s0 = s[0], s1 = s[1];
      xs[rr][cc] = s0; xs[rr][cc + 1] = s1;
      if (xbf) {
        us2 h = {f2bf(s0), f2bf(s1)};
        *(us2*)(xbf + (size_t)(t0 + rr) * DM + k0 + cc) = h;
      }
    }
    {
      int rr = tid >> 3, cc = (tid & 7) * 4;
      float4 v = *(const float4*)(gw + (size_t)(k0 + rr) * NE + cc);
      gs[rr][cc] = v.x; gs[rr][cc + 1] = v.y; gs[rr][cc + 2] = v.z; gs[rr][cc + 3] = v.w;
    }
    __syncthreads();
    #pragma unroll
    for (int kk = 0; kk < 32; ++kk) {
      double a = (double)xs[r][kk];
      a0 += a * (double)gs[kk][e0];
      a1 += a * (double)gs[kk][e0 + 1];
    }
    __syncthreads();
  }
  logits[(size_t)(t0 + r) * NE + e0]     = (float)a0 + gb[e0];
  logits[(size_t)(t0 + r) * NE + e0 + 1] = (float)a1 + gb[e0 + 1];
}

// ---------------- softmax + top2 + scatter ----------------
__global__ void topk_kernel(const float* __restrict__ logits, int* __restrict__ counts,
                            int* __restrict__ lists, float* __restrict__ wlists)
{
  int t = blockIdx.x * blockDim.x + threadIdx.x;
  if (t >= NTOK) return;
  float l[32];
  const float4* lp = (const float4*)(logits + (size_t)t * NE);
  #pragma unroll
  for (int i = 0; i < 8; ++i) {
    float4 v = lp[i];
    l[i*4] = v.x; l[i*4+1] = v.y; l[i*4+2] = v.z; l[i*4+3] = v.w;
  }
  float mx = l[0];
  #pragma unroll
  for (int e = 1; e < 32; ++e) mx = fmaxf(mx, l[e]);
  float s = 0.f;
  #pragma unroll
  for (int e = 0; e < 32; ++e) s += expf(l[e] - mx);
  int i1 = 0; float b1 = l[0];
  #pragma unroll
  for (int e = 1; e < 32; ++e) if (l[e] > b1) { b1 = l[e]; i1 = e; }
  int i2 = -1; float b2 = -3.4e38f;
  #pragma unroll
  for (int e = 0; e < 32; ++e) if (e != i1 && l[e] > b2) { b2 = l[e]; i2 = e; }
  float p1 = expf(b1 - mx) / s;
  float p2 = expf(b2 - mx) / s;
  int pos = atomicAdd(&counts[i1], 1);
  lists [(size_t)i1 * NTOK + pos] = t;
  wlists[(size_t)i1 * NTOK + pos] = p1;
  pos = atomicAdd(&counts[32 + i2], 1);
  lists [(size_t)(32 + i2) * NTOK + pos] = t;
  wlists[(size_t)(32 + i2) * NTOK + pos] = p2;
}

// ================================================================
// ======================= OLD PATH (fallback) =====================
// ================================================================
__global__ void scan_kernel(const int* __restrict__ counts, int* __restrict__ seg_count,
                            int* __restrict__ seg_hbase, int2* __restrict__ tableA,
                            int2* __restrict__ tableR0, int2* __restrict__ tableR1,
                            int* __restrict__ tns)
{
  if (threadIdx.x != 0 || blockIdx.x != 0) return;
  seg_count[0] = NTOK; seg_hbase[0] = 0;
  seg_count[1] = NTOK; seg_hbase[1] = NTOK;
  int base = 2 * NTOK;
  for (int li = 0; li < 64; ++li) {
    int c = counts[li];
    seg_count[2 + li] = c; seg_hbase[2 + li] = base; base += c;
  }
  int nA = 0;
  for (int s = 0; s < 66; ++s) {
    int c = seg_count[s];
    for (int m0 = 0; m0 < c; m0 += 64) { tableA[nA].x = s; tableA[nA].y = m0; ++nA; }
  }
  int nR0 = 0;
  for (int li = 0; li < 32; ++li)
    for (int m0 = 0; m0 < counts[li]; m0 += 64) { tableR0[nR0].x = li; tableR0[nR0].y = m0; ++nR0; }
  int nR1 = 0;
  for (int li = 32; li < 64; ++li)
    for (int m0 = 0; m0 < counts[li]; m0 += 64) { tableR1[nR1].x = li; tableR1[nR1].y = m0; ++nR1; }
  tns[0] = nA; tns[1] = nR0; tns[2] = nR1;
}

__global__ __launch_bounds__(256) void ffn1_kernel(
    const float* __restrict__ x,
    const float* __restrict__ sw1, const float* __restrict__ sb1,
    const float* __restrict__ rw1, const float* __restrict__ rb1,
    const int* __restrict__ lists,
    const int* __restrict__ seg_count, const int* __restrict__ seg_hbase,
    const int2* __restrict__ tableA, const int* __restrict__ tns,
    unsigned short* __restrict__ hbuf)
{
  if ((int)blockIdx.x >= tns[0]) return;
  int2 ent = tableA[blockIdx.x];
  int seg = ent.x, m0 = ent.y;
  int cnt = seg_count[seg];
  int hbase = seg_hbase[seg];
  int n0 = blockIdx.y * 64;
  const float *w1, *b1;
  if (seg < 2) { w1 = sw1 + (size_t)seg * DM * FD; b1 = sb1 + (size_t)seg * FD; }
  else { int e = (seg - 2) & 31; w1 = rw1 + (size_t)e * DM * FD; b1 = rb1 + (size_t)e * FD; }
  __shared__ int toks[64];
  __shared__ unsigned short As[64][44];
  __shared__ unsigned short Bs[64][44];
  int tid = threadIdx.x;
  if (tid < 64) {
    int i = m0 + tid;
    int tk = 0;
    if (i < cnt) tk = (seg < 2) ? i : lists[(size_t)(seg - 2) * NTOK + i];
    toks[tid] = tk;
  }
  __syncthreads();
  int lane = tid & 63, wave = tid >> 6;
  int wr = (wave >> 1) * 32, wc = (wave & 1) * 32;
  int l15 = lane & 15, kb = (lane >> 4) * 8;
  f32x4 zz = {0.f, 0.f, 0.f, 0.f};
  f32x4 acc[2][2];
  #pragma unroll
  for (int i = 0; i < 2; ++i)
    #pragma unroll
    for (int j = 0; j < 2; ++j) acc[i][j] = zz;
  int ar = tid >> 2, ac = (tid & 3) * 8;
  const float* axp = x + (size_t)toks[ar] * DM + ac;
  int br = tid >> 3, bc = (tid & 7) * 8;
  const float* bwp = w1 + (size_t)br * FD + n0 + bc;
  for (int k0 = 0; k0 < DM; k0 += 32) {
    float4 a0 = *(const float4*)(axp + k0);
    float4 a1 = *(const float4*)(axp + k0 + 4);
    float4 w0 = *(const float4*)bwp;
    float4 w4 = *(const float4*)(bwp + 4);
    bwp += (size_t)32 * FD;
    us4 pa0 = {f2bf(a0.x), f2bf(a0.y), f2bf(a0.z), f2bf(a0.w)};
    us4 pa1 = {f2bf(a1.x), f2bf(a1.y), f2bf(a1.z), f2bf(a1.w)};
    *(us4*)&As[ar][ac] = pa0;
    *(us4*)&As[ar][ac + 4] = pa1;
    Bs[bc + 0][br] = f2bf(w0.x); Bs[bc + 1][br] = f2bf(w0.y);
    Bs[bc + 2][br] = f2bf(w0.z); Bs[bc + 3][br] = f2bf(w0.w);
    Bs[bc + 4][br] = f2bf(w4.x); Bs[bc + 5][br] = f2bf(w4.y);
    Bs[bc + 6][br] = f2bf(w4.z); Bs[bc + 7][br] = f2bf(w4.w);
    __syncthreads();
    bf16x8 af0 = ldf(&As[wr + l15][kb]);
    bf16x8 af1 = ldf(&As[wr + 16 + l15][kb]);
    bf16x8 bf0 = ldf(&Bs[wc + l15][kb]);
    bf16x8 bf1 = ldf(&Bs[wc + 16 + l15][kb]);
    acc[0][0] = mfma16(af0, bf0, acc[0][0]);
    acc[0][1] = mfma16(af0, bf1, acc[0][1]);
    acc[1][0] = mfma16(af1, bf0, acc[1][0]);
    acc[1][1] = mfma16(af1, bf1, acc[1][1]);
    __syncthreads();
  }
  int rb4 = (lane >> 4) * 4;
  #pragma unroll
  for (int mi = 0; mi < 2; ++mi) {
    #pragma unroll
    for (int rg = 0; rg < 4; ++rg) {
      int gi = m0 + wr + mi * 16 + rb4 + rg;
      if (gi < cnt) {
        #pragma unroll
        for (int ni = 0; ni < 2; ++ni) {
          int ncol = n0 + wc + ni * 16 + l15;
          float v = acc[mi][ni][rg] + b1[ncol];
          hbuf[(size_t)(hbase + gi) * FD + ncol] = f2bf(gelu_f(v));
        }
      }
    }
  }
}

__global__ __launch_bounds__(256) void ffn2_shared_kernel(
    const unsigned short* __restrict__ hbuf,
    const float* __restrict__ sw2, const float* __restrict__ sb2,
    float* __restrict__ out)
{
  int m0 = blockIdx.x * 64;
  int n0 = blockIdx.y * 64;
  __shared__ unsigned short As[64][44];
  __shared__ unsigned short Bs[64][44];
  int tid = threadIdx.x;
  int lane = tid & 63, wave = tid >> 6;
  int wr = (wave >> 1) * 32, wc = (wave & 1) * 32;
  int l15 = lane & 15, kb = (lane >> 4) * 8;
  f32x4 zz = {0.f, 0.f, 0.f, 0.f};
  f32x4 acc[2][2];
  #pragma unroll
  for (int i = 0; i < 2; ++i)
    #pragma unroll
    for (int j = 0; j < 2; ++j) acc[i][j] = zz;
  int ar = tid >> 2, ac = (tid & 3) * 8;
  int br = tid >> 3, bc = (tid & 7) * 8;
  const float* bwp = sw2 + (size_t)br * DM + n0 + bc;
  for (int k0 = 0; k0 < 2 * FD; k0 += 32) {
    int side = (k0 >= FD) ? 1 : 0;
    const unsigned short* ap =
        hbuf + (size_t)(side * NTOK + m0 + ar) * FD + (k0 - side * FD) + ac;
    us8 av = *(const us8*)ap;
    float4 w0 = *(const float4*)bwp;
    float4 w4 = *(const float4*)(bwp + 4);
    bwp += (size_t)32 * DM;
    us4 alo = {av[0], av[1], av[2], av[3]};
    us4 ahi = {av[4], av[5], av[6], av[7]};
    *(us4*)&As[ar][ac] = alo;
    *(us4*)&As[ar][ac + 4] = ahi;
    Bs[bc + 0][br] = f2bf(w0.x); Bs[bc + 1][br] = f2bf(w0.y);
    Bs[bc + 2][br] = f2bf(w0.z); Bs[bc + 3][br] = f2bf(w0.w);
    Bs[bc + 4][br] = f2bf(w4.x); Bs[bc + 5][br] = f2bf(w4.y);
    Bs[bc + 6][br] = f2bf(w4.z); Bs[bc + 7][br] = f2bf(w4.w);
    __syncthreads();
    bf16x8 af0 = ldf(&As[wr + l15][kb]);
    bf16x8 af1 = ldf(&As[wr + 16 + l15][kb]);
    bf16x8 bf0 = ldf(&Bs[wc + l15][kb]);
    bf16x8 bf1 = ldf(&Bs[wc + 16 + l15][kb]);
    acc[0][0] = mfma16(af0, bf0, acc[0][0]);
    acc[0][1] = mfma16(af0, bf1, acc[0][1]);
    acc[1][0] = mfma16(af1, bf0, acc[1][0]);
    acc[1][1] = mfma16(af1, bf1, acc[1][1]);
    __syncthreads();
  }
  int rb4 = (lane >> 4) * 4;
  #pragma unroll
  for (int mi = 0; mi < 2; ++mi) {
    #pragma unroll
    for (int rg = 0; rg < 4; ++rg) {
      int row = m0 + wr + mi * 16 + rb4 + rg;
      #pragma unroll
      for (int ni = 0; ni < 2; ++ni) {
        int ncol = n0 + wc + ni * 16 + l15;
        out[(size_t)row * DM + ncol] = acc[mi][ni][rg] + sb2[ncol] + sb2[DM + ncol];
      }
    }
  }
}

__global__ __launch_bounds__(256) void ffn2_routed_kernel(
    const unsigned short* __restrict__ hbuf,
    const float* __restrict__ rw2, const float* __restrict__ rb2,
    const int* __restrict__ lists, const float* __restrict__ wlists,
    const int* __restrict__ counts, const int* __restrict__ seg_hbase,
    const int2* __restrict__ tableR, const int* __restrict__ tns, int tidx,
    float* __restrict__ out)
{
  if ((int)blockIdx.x >= tns[tidx]) return;
  int2 ent = tableR[blockIdx.x];
  int li = ent.x, m0 = ent.y;
  int cnt = counts[li];
  int hbase = seg_hbase[2 + li];
  int e = li & 31;
  int n0 = blockIdx.y * 64;
  const float* w2 = rw2 + (size_t)e * FD * DM;
  const float* b2 = rb2 + (size_t)e * DM;
  __shared__ unsigned short As[64][44];
  __shared__ unsigned short Bs[64][44];
  int tid = threadIdx.x;
  int lane = tid & 63, wave = tid >> 6;
  int wr = (wave >> 1) * 32, wc = (wave & 1) * 32;
  int l15 = lane & 15, kb = (lane >> 4) * 8;
  f32x4 zz = {0.f, 0.f, 0.f, 0.f};
  f32x4 acc[2][2];
  #pragma unroll
  for (int i = 0; i < 2; ++i)
    #pragma unroll
    for (int j = 0; j < 2; ++j) acc[i][j] = zz;
  int ar = tid >> 2, ac = (tid & 3) * 8;
  const unsigned short* ap = hbuf + (size_t)(hbase + m0 + ar) * FD + ac;
  int br = tid >> 3, bc = (tid & 7) * 8;
  const float* bwp = w2 + (size_t)br * DM + n0 + bc;
  for (int k0 = 0; k0 < FD; k0 += 32) {
    us8 av = *(const us8*)(ap + k0);
    float4 w0 = *(const float4*)bwp;
    float4 w4 = *(const float4*)(bwp + 4);
    bwp += (size_t)32 * DM;
    us4 alo = {av[0], av[1], av[2], av[3]};
    us4 ahi = {av[4], av[5], av[6], av[7]};
    *(us4*)&As[ar][ac] = alo;
    *(us4*)&As[ar][ac + 4] = ahi;
    Bs[bc + 0][br] = f2bf(w0.x); Bs[bc + 1][br] = f2bf(w0.y);
    Bs[bc + 2][br] = f2bf(w0.z); Bs[bc + 3][br] = f2bf(w0.w);
    Bs[bc + 4][br] = f2bf(w4.x); Bs[bc + 5][br] = f2bf(w4.y);
    Bs[bc + 6][br] = f2bf(w4.z); Bs[bc + 7][br] = f2bf(w4.w);
    __syncthreads();
    bf16x8 af0 = ldf(&As[wr + l15][kb]);
    bf16x8 af1 = ldf(&As[wr + 16 + l15][kb]);
    bf16x8 bf0 = ldf(&Bs[wc + l15][kb]);
    bf16x8 bf1 = ldf(&Bs[wc + 16 + l15][kb]);
    acc[0][0] = mfma16(af0, bf0, acc[0][0]);
    acc[0][1] = mfma16(af0, bf1, acc[0][1]);
    acc[1][0] = mfma16(af1, bf0, acc[1][0]);
    acc[1][1] = mfma16(af1, bf1, acc[1][1]);
    __syncthreads();
  }
  int rb4 = (lane >> 4) * 4;
  #pragma unroll
  for (int mi = 0; mi < 2; ++mi) {
    #pragma unroll
    for (int rg = 0; rg < 4; ++rg) {
      int gi = m0 + wr + mi * 16 + rb4 + rg;
      if (gi < cnt) {
        int tok = lists[(size_t)li * NTOK + gi];
        float wgt = wlists[(size_t)li * NTOK + gi];
        #pragma unroll
        for (int ni = 0; ni < 2; ++ni) {
          int ncol = n0 + wc + ni * 16 + l15;
          float v = (acc[mi][ni][rg] + b2[ncol]) * wgt;
          out[(size_t)tok * DM + ncol] += v;
        }
      }
    }
  }
}

// ================================================================
// ========================= NEW PATH =============================
// ================================================================

// table builder
__global__ void scan_v3(const int* __restrict__ counts, int* __restrict__ hbase_g,
                        int2* __restrict__ tableA, int2* __restrict__ tableR0,
                        int2* __restrict__ tableR1, int* __restrict__ tns)
{
  __shared__ int cnt[64], tprefA[64], tpref0[32], tpref1[32], hpref[64];
  int t = threadIdx.x;
  if (t < 64) cnt[t] = counts[t];
  __syncthreads();
  if (t == 0) {
    int hb = 2 * NTOK, ta = 128, t0 = 0, t1 = 0;
    for (int i = 0; i < 64; ++i) {
      int nt = (cnt[i] + 63) >> 6;
      hpref[i] = hb; hb += cnt[i];
      tprefA[i] = ta; ta += nt;
      if (i < 32) { tpref0[i] = t0; t0 += nt; }
      else        { tpref1[i - 32] = t1; t1 += nt; }
    }
    tns[0] = ta; tns[1] = t0; tns[2] = t1;
  }
  __syncthreads();
  if (t < 128) {
    int2 ent; ent.x = t >> 6; ent.y = (t & 63) * 64;
    tableA[t] = ent;
  }
  if (t < 64) {
    hbase_g[t] = hpref[t];
    int nt = (cnt[t] + 63) >> 6;
    for (int j = 0; j < nt; ++j) {
      int2 ent; ent.x = 2 + t; ent.y = j * 64;
      tableA[tprefA[t] + j] = ent;
      int2 entR; entR.x = t; entR.y = j * 64;
      if (t < 32) tableR0[tpref0[t] + j] = entR;
      else        tableR1[tpref1[t - 32] + j] = entR;
    }
  }
}

// transpose-convert w1 f32 [seg][k][n] -> bf16 [seg][n][k]
// LDS swizzle: element (row,c) lives at col c ^ (((row>>4)&3)<<4).
// float4 writes stay 16B-aligned (XOR touches bits 4-5 of column index only);
// derived bank spread: reads/writes become 2-way (free) vs 4-way before.
__global__ __launch_bounds__(256) void conv_w1_v2(
    const float* __restrict__ sw1, const float* __restrict__ rw1,
    unsigned short* __restrict__ w1T)
{
  int seg = blockIdx.x;
  int k0 = blockIdx.y * 64;
  int n0 = blockIdx.z * 64;
  const float* src = (seg < 2) ? sw1 + (size_t)seg * DM * FD
                               : rw1 + (size_t)(seg - 2) * DM * FD;
  __shared__ float ls[64][68];
  int tid = threadIdx.x;
  int r = tid >> 4, c4 = (tid & 15) * 4;
  #pragma unroll
  for (int p = 0; p < 4; ++p) {
    int row = r + p * 16;
    float4 v = *(const float4*)(src + (size_t)(k0 + row) * FD + n0 + c4);
    *(float4*)&ls[row][c4 ^ (((row >> 4) & 3) << 4)] = v;
  }
  __syncthreads();
  int n = tid >> 2, kseg = (tid & 3) * 16;
  int swz = ((kseg >> 4) & 3) << 4;          // row>>4 == kseg>>4 for j<16
  unsigned short tmp[16];
  #pragma unroll
  for (int j = 0; j < 16; ++j) tmp[j] = f2bf(ls[kseg + j][n ^ swz]);
  unsigned short* dst = w1T + (size_t)seg * FD * DM + (size_t)(n0 + n) * DM + k0 + kseg;
  us8 o0 = {tmp[0], tmp[1], tmp[2], tmp[3], tmp[4], tmp[5], tmp[6], tmp[7]};
  us8 o1 = {tmp[8], tmp[9], tmp[10], tmp[11], tmp[12], tmp[13], tmp[14], tmp[15]};
  *(us8*)dst = o0;
  *(us8*)(dst + 8) = o1;
}

// transpose-convert w2 (same swizzle as conv_w1)
__global__ __launch_bounds__(256) void conv_w2_v2(
    const float* __restrict__ sw2, const float* __restrict__ rw2,
    unsigned short* __restrict__ w2sT, unsigned short* __restrict__ w2rT)
{
  int e = blockIdx.x;
  int K = (e == 0) ? 2 * FD : FD;
  int k0 = blockIdx.y * 64;
  if (k0 >= K) return;
  int n0 = blockIdx.z * 64;
  const float* src = (e == 0) ? sw2 : rw2 + (size_t)(e - 1) * FD * DM;
  unsigned short* dstb = (e == 0) ? w2sT : w2rT + (size_t)(e - 1) * DM * FD;
  __shared__ float ls[64][68];
  int tid = threadIdx.x;
  int r = tid >> 4, c4 = (tid & 15) * 4;
  #pragma unroll
  for (int p = 0; p < 4; ++p) {
    int row = r + p * 16;
    float4 v = *(const float4*)(src + (size_t)(k0 + row) * DM + n0 + c4);
    *(float4*)&ls[row][c4 ^ (((row >> 4) & 3) << 4)] = v;
  }
  __syncthreads();
  int n = tid >> 2, kseg = (tid & 3) * 16;
  int swz = ((kseg >> 4) & 3) << 4;
  unsigned short tmp[16];
  #pragma unroll
  for (int j = 0; j < 16; ++j) tmp[j] = f2bf(ls[kseg + j][n ^ swz]);
  unsigned short* dst = dstb + (size_t)(n0 + n) * K + k0 + kseg;
  us8 o0 = {tmp[0], tmp[1], tmp[2], tmp[3], tmp[4], tmp[5], tmp[6], tmp[7]};
  us8 o1 = {tmp[8], tmp[9], tmp[10], tmp[11], tmp[12], tmp[13], tmp[14], tmp[15]};
  *(us8*)dst = o0;
  *(us8*)(dst + 8) = o1;
}

// unified ffn1: 64x128 tiles, K=5120, double-buffered LDS (1 barrier per K-step)
__global__ __launch_bounds__(256) void ffn1_v3(
    const unsigned short* __restrict__ xbf, const unsigned short* __restrict__ w1T,
    const float* __restrict__ sb1, const float* __restrict__ rb1,
    const int* __restrict__ lists, const int* __restrict__ counts,
    const int* __restrict__ hbase_g, const int2* __restrict__ tableA,
    const int* __restrict__ tns, unsigned short* __restrict__ hbuf)
{
  if ((int)blockIdx.x >= tns[0]) return;
  int2 ent = tableA[blockIdx.x];
  int seg = ent.x, m0 = ent.y;
  int cnt, hbase, wseg;
  const float* b1;
  if (seg < 2) {
    cnt = NTOK; hbase = seg * NTOK; b1 = sb1 + seg * FD; wseg = seg;
  } else {
    int li = seg - 2;
    int e = li & 31;
    cnt = counts[li]; hbase = hbase_g[li];
    b1 = rb1 + (size_t)e * FD;
    wseg = 2 + e;                        // w1T has 34 segs (li>=32 maps to same expert)
  }
  int n0 = blockIdx.y * 128;
  const unsigned short* w1 = w1T + (size_t)wseg * FD * DM;

  __shared__ int toks[64];
  __shared__ __align__(16) unsigned short As[2][64 * 64];
  __shared__ __align__(16) unsigned short Bs[2][128 * 64];

  int tid = threadIdx.x;
  if (tid < 64) {
    int i = m0 + tid;
    int tk;
    if (seg < 2) tk = (i < cnt) ? i : 0;
    else tk = (i < cnt) ? lists[(size_t)(seg - 2) * NTOK + i] : 0;
    toks[tid] = tk;
  }
  __syncthreads();

  int lane = tid & 63, wave = tid >> 6;
  int wr = (wave >> 1) * 32, wc = (wave & 1) * 64;
  int l15 = lane & 15, l4 = lane >> 4;

  f32x4 zz = {0.f, 0.f, 0.f, 0.f};
  f32x4 acc[2][4];
  #pragma unroll
  for (int i = 0; i < 2; ++i)
    #pragma unroll
    for (int j = 0; j < 4; ++j) acc[i][j] = zz;

  int ar0 = tid >> 3, ag0 = tid & 7;
  int arw[2] = {ar0, 32 + ar0};
  const unsigned short* asrc[2];
  asrc[0] = xbf + (size_t)toks[arw[0]] * DM + ag0 * 8;
  asrc[1] = xbf + (size_t)toks[arw[1]] * DM + ag0 * 8;
  const unsigned short* bsrc[4];
  int brow[4];
  #pragma unroll
  for (int p = 0; p < 4; ++p) {
    int idx = p * 256 + tid;
    brow[p] = idx >> 3;
    bsrc[p] = w1 + (size_t)(n0 + brow[p]) * DM + (idx & 7) * 8;
  }

  // prologue: stage k0=0 into buffer 0
  {
    us8 va[2], vb[4];
    #pragma unroll
    for (int p = 0; p < 2; ++p) va[p] = *(const us8*)(asrc[p]);
    #pragma unroll
    for (int p = 0; p < 4; ++p) vb[p] = *(const us8*)(bsrc[p]);
    #pragma unroll
    for (int p = 0; p < 2; ++p) fragst(As[0], arw[p], ag0, va[p]);
    #pragma unroll
    for (int p = 0; p < 4; ++p) fragst(Bs[0], brow[p], ag0, vb[p]);
  }
  __syncthreads();

  int cur = 0;
  for (int k0 = 0; k0 < DM; k0 += 64) {
    int nk = k0 + 64;
    us8 va1[2], vb1[4];
    if (nk < DM) {
      #pragma unroll
      for (int p = 0; p < 2; ++p) va1[p] = *(const us8*)(asrc[p] + nk);
      #pragma unroll
      for (int p = 0; p < 4; ++p) vb1[p] = *(const us8*)(bsrc[p] + nk);
    }
    const unsigned short* Ac = As[cur];
    const unsigned short* Bc = Bs[cur];
    #pragma unroll
    for (int kk = 0; kk < 2; ++kk) {
      bf16x8 af[2], bfr[4];
      #pragma unroll
      for (int mi = 0; mi < 2; ++mi) af[mi] = fragld(Ac, wr + mi * 16 + l15, kk * 4 + l4);
      #pragma unroll
      for (int ni = 0; ni < 4; ++ni) bfr[ni] = fragld(Bc, wc + ni * 16 + l15, kk * 4 + l4);
      #pragma unroll
      for (int mi = 0; mi < 2; ++mi)
        #pragma unroll
        for (int ni = 0; ni < 4; ++ni) acc[mi][ni] = mfma16(af[mi], bfr[ni], acc[mi][ni]);
    }
    if (nk < DM) {
      unsigned short* An = As[cur ^ 1];
      unsigned short* Bn = Bs[cur ^ 1];
      #pragma unroll
      for (int p = 0; p < 2; ++p) fragst(An, arw[p], ag0, va1[p]);
      #pragma unroll
      for (int p = 0; p < 4; ++p) fragst(Bn, brow[p], ag0, vb1[p]);
    }
    __syncthreads();
    cur ^= 1;
  }

  int rb4 = l4 * 4;
  #pragma unroll
  for (int mi = 0; mi < 2; ++mi) {
    #pragma unroll
    for (int rg = 0; rg < 4; ++rg) {
      int gi = m0 + wr + mi * 16 + rb4 + rg;
      if (gi < cnt) {
        #pragma unroll
        for (int ni = 0; ni < 4; ++ni) {
          int ncol = n0 + wc + ni * 16 + l15;
          float v = acc[mi][ni][rg] + b1[ncol];
          hbuf[(size_t)(hbase + gi) * FD + ncol] = f2bf(gelu_f(v));
        }
      }
    }
  }
}

// ffn2 shared: dense 128x128, K=768, double-buffered
__global__ __launch_bounds__(256) void ffn2_shared_v2(
    const unsigned short* __restrict__ hbuf, const unsigned short* __restrict__ w2sT,
    const float* __restrict__ sb2, float* __restrict__ out)
{
  int m0 = blockIdx.x * 128;
  int n0 = blockIdx.y * 128;

  __shared__ __align__(16) unsigned short As[2][128 * 64];
  __shared__ __align__(16) unsigned short Bs[2][128 * 64];

  int tid = threadIdx.x;
  int lane = tid & 63, wave = tid >> 6;
  int wr = (wave >> 1) * 64, wc = (wave & 1) * 64;
  int l15 = lane & 15, l4 = lane >> 4;

  f32x4 zz = {0.f, 0.f, 0.f, 0.f};
  f32x4 acc[4][4];
  #pragma unroll
  for (int i = 0; i < 4; ++i)
    #pragma unroll
    for (int j = 0; j < 4; ++j) acc[i][j] = zz;

  int prow[4], pg[4];
  #pragma unroll
  for (int p = 0; p < 4; ++p) {
    int idx = p * 256 + tid;
    prow[p] = idx >> 3; pg[p] = idx & 7;
  }

  // prologue k0=0 (side 0)
  {
    us8 va[4], vb[4];
    #pragma unroll
    for (int p = 0; p < 4; ++p)
      va[p] = *(const us8*)(hbuf + (size_t)(m0 + prow[p]) * FD + pg[p] * 8);
    #pragma unroll
    for (int p = 0; p < 4; ++p)
      vb[p] = *(const us8*)(w2sT + (size_t)(n0 + prow[p]) * (2 * FD) + pg[p] * 8);
    #pragma unroll
    for (int p = 0; p < 4; ++p) fragst(As[0], prow[p], pg[p], va[p]);
    #pragma unroll
    for (int p = 0; p < 4; ++p) fragst(Bs[0], prow[p], pg[p], vb[p]);
  }
  __syncthreads();

  int cur = 0;
  for (int k0 = 0; k0 < 2 * FD; k0 += 64) {
    int nk = k0 + 64;
    us8 va1[4], vb1[4];
    if (nk < 2 * FD) {
      int side = (nk >= FD) ? 1 : 0;
      int kk0 = nk - side * FD;
      #pragma unroll
      for (int p = 0; p < 4; ++p)
        va1[p] = *(const us8*)(hbuf + (size_t)(side * NTOK + m0 + prow[p]) * FD + kk0 + pg[p] * 8);
      #pragma unroll
      for (int p = 0; p < 4; ++p)
        vb1[p] = *(const us8*)(w2sT + (size_t)(n0 + prow[p]) * (2 * FD) + nk + pg[p] * 8);
    }
    const unsigned short* Ac = As[cur];
    const unsigned short* Bc = Bs[cur];
    #pragma unroll
    for (int kk = 0; kk < 2; ++kk) {
      bf16x8 af[4], bfr[4];
      #pragma unroll
      for (int mi = 0; mi < 4; ++mi) af[mi] = fragld(Ac, wr + mi * 16 + l15, kk * 4 + l4);
      #pragma unroll
      for (int ni = 0; ni < 4; ++ni) bfr[ni] = fragld(Bc, wc + ni * 16 + l15, kk * 4 + l4);
      #pragma unroll
      for (int mi = 0; mi < 4; ++mi)
        #pragma unroll
        for (int ni = 0; ni < 4; ++ni) acc[mi][ni] = mfma16(af[mi], bfr[ni], acc[mi][ni]);
    }
    if (nk < 2 * FD) {
      unsigned short* An = As[cur ^ 1];
      unsigned short* Bn = Bs[cur ^ 1];
      #pragma unroll
      for (int p = 0; p < 4; ++p) fragst(An, prow[p], pg[p], va1[p]);
      #pragma unroll
      for (int p = 0; p < 4; ++p) fragst(Bn, prow[p], pg[p], vb1[p]);
    }
    __syncthreads();
    cur ^= 1;
  }

  int rb4 = l4 * 4;
  #pragma unroll
  for (int mi = 0; mi < 4; ++mi) {
    #pragma unroll
    for (int rg = 0; rg < 4; ++rg) {
      int row = m0 + wr + mi * 16 + rb4 + rg;
      #pragma unroll
      for (int ni = 0; ni < 4; ++ni) {
        int ncol = n0 + wc + ni * 16 + l15;
        out[(size_t)row * DM + ncol] = acc[mi][ni][rg] + sb2[ncol] + sb2[DM + ncol];
      }
    }
  }
}

// ffn2 routed: gathered 64x128, K=384, double-buffered, out += w*(h@w2+b2)
__global__ __launch_bounds__(256) void ffn2_routed_v2(
    const unsigned short* __restrict__ hbuf, const unsigned short* __restrict__ w2rT,
    const float* __restrict__ rb2, const int* __restrict__ lists,
    const float* __restrict__ wlists, const int* __restrict__ counts,
    const int* __restrict__ hbase_g, const int2* __restrict__ tableR,
    const int* __restrict__ tns, int tidx, float* __restrict__ out)
{
  if ((int)blockIdx.x >= tns[tidx]) return;
  int2 ent = tableR[blockIdx.x];
  int li = ent.x, m0 = ent.y;
  int cnt = counts[li];
  int hbase = hbase_g[li];
  int e = li & 31;
  int n0 = blockIdx.y * 128;
  const unsigned short* w2 = w2rT + (size_t)e * DM * FD;

  __shared__ __align__(16) unsigned short As[2][64 * 64];
  __shared__ __align__(16) unsigned short Bs[2][128 * 64];

  int tid = threadIdx.x;
  int lane = tid & 63, wave = tid >> 6;
  int wr = (wave >> 1) * 32, wc = (wave & 1) * 64;
  int l15 = lane & 15, l4 = lane >> 4;

  f32x4 zz = {0.f, 0.f, 0.f, 0.f};
  f32x4 acc[2][4];
  #pragma unroll
  for (int i = 0; i < 2; ++i)
    #pragma unroll
    for (int j = 0; j < 4; ++j) acc[i][j] = zz;

  int ar0 = tid >> 3, ag0 = tid & 7;
  int arw[2] = {ar0, 32 + ar0};
  const unsigned short* asrc[2];
  asrc[0] = hbuf + (size_t)(hbase + m0 + arw[0]) * FD + ag0 * 8;
  asrc[1] = hbuf + (size_t)(hbase + m0 + arw[1]) * FD + ag0 * 8;
  const unsigned short* bsrc[4];
  int brow[4];
  #pragma unroll
  for (int p = 0; p < 4; ++p) {
    int idx = p * 256 + tid;
    brow[p] = idx >> 3;
    bsrc[p] = w2 + (size_t)(n0 + brow[p]) * FD + (idx & 7) * 8;
  }

  {
    us8 va[2], vb[4];
    #pragma unroll
    for (int p = 0; p < 2; ++p) va[p] = *(const us8*)(asrc[p]);
    #pragma unroll
    for (int p = 0; p < 4; ++p) vb[p] = *(const us8*)(bsrc[p]);
    #pragma unroll
    for (int p = 0; p < 2; ++p) fragst(As[0], arw[p], ag0, va[p]);
    #pragma unroll
    for (int p = 0; p < 4; ++p) fragst(Bs[0], brow[p], ag0, vb[p]);
  }
  __syncthreads();

  int cur = 0;
  for (int k0 = 0; k0 < FD; k0 += 64) {
    int nk = k0 + 64;
    us8 va1[2], vb1[4];
    if (nk < FD) {
      #pragma unroll
      for (int p = 0; p < 2; ++p) va1[p] = *(const us8*)(asrc[p] + nk);
      #pragma unroll
      for (int p = 0; p < 4; ++p) vb1[p] = *(const us8*)(bsrc[p] + nk);
    }
    const unsigned short* Ac = As[cur];
    const unsigned short* Bc = Bs[cur];
    #pragma unroll
    for (int kk = 0; kk < 2; ++kk) {
      bf16x8 af[2], bfr[4];
      #pragma unroll
      for (int mi = 0; mi < 2; ++mi) af[mi] = fragld(Ac, wr + mi * 16 + l15, kk * 4 + l4);
      #pragma unroll
      for (int ni = 0; ni < 4; ++ni) bfr[ni] = fragld(Bc, wc + ni * 16 + l15, kk * 4 + l4);
      #pragma unroll
      for (int mi = 0; mi < 2; ++mi)
        #pragma unroll
        for (int ni = 0; ni < 4; ++ni) acc[mi][ni] = mfma16(af[mi], bfr[ni], acc[mi][ni]);
    }
    if (nk < FD) {
      unsigned short* An = As[cur ^ 1];
      unsigned short* Bn = Bs[cur ^ 1];
      #pragma unroll
      for (int p = 0; p < 2; ++p) fragst(An, arw[p], ag0, va1[p]);
      #pragma unroll
      for (int p = 0; p < 4; ++p) fragst(Bn, brow[p], ag0, vb1[p]);
    }
    __syncthreads();
    cur ^= 1;
  }

  int rb4 = l4 * 4;
  #pragma unroll
  for (int mi = 0; mi < 2; ++mi) {
    #pragma unroll
    for (int rg = 0; rg < 4; ++rg) {
      int gi = m0 + wr + mi * 16 + rb4 + rg;
      if (gi < cnt) {
        int tok = lists[(size_t)li * NTOK + gi];
        float wgt = wlists[(size_t)li * NTOK + gi];
        #pragma unroll
        for (int ni = 0; ni < 4; ++ni) {
          int ncol = n0 + wc + ni * 16 + l15;
          float v = (acc[mi][ni][rg] + rb2[(size_t)e * DM + ncol]) * wgt;
          out[(size_t)tok * DM + ncol] += v;
        }
      }
    }
  }
}

// ---------------- launch ----------------
extern "C" void kernel_launch(void* const* d_in, const int* in_sizes, int n_in,
                              void* d_out, int out_size, void* d_ws, size_t ws_size,
                              hipStream_t stream) {
  const float* x   = (const float*)d_in[0];
  const float* sw1 = (const float*)d_in[1];
  const float* sb1 = (const float*)d_in[2];
  const float* sw2 = (const float*)d_in[3];
  const float* sb2 = (const float*)d_in[4];
  const float* rw1 = (const float*)d_in[5];
  const float* rb1 = (const float*)d_in[6];
  const float* rw2 = (const float*)d_in[7];
  const float* rb2 = (const float*)d_in[8];
  const float* gw  = (const float*)d_in[9];
  const float* gb  = (const float*)d_in[10];
  float* out = (float*)d_out;
  char* ws = (char*)d_ws;

  if (ws_size >= WS_NEW) {
    float* logits  = (float*)(ws + L_LOGITS);
    int* counts    = (int*)(ws + L_COUNTS);
    int* hbase_g   = (int*)(ws + L_HBASE);
    int2* tableA   = (int2*)(ws + L_TABA);
    int2* tableR0  = (int2*)(ws + L_TABR0);
    int2* tableR1  = (int2*)(ws + L_TABR1);
    int* tns       = (int*)(ws + L_TNS);
    int* lists     = (int*)(ws + L_LISTS);
    float* wlists  = (float*)(ws + L_WLIST);
    unsigned short* hbuf = (unsigned short*)(ws + L_HBUF);
    unsigned short* xbf  = (unsigned short*)(ws + L_XBF);
    unsigned short* w1T  = (unsigned short*)(ws + L_W1T);
    unsigned short* w2sT = (unsigned short*)(ws + L_W2ST);
    unsigned short* w2rT = (unsigned short*)(ws + L_W2RT);

    hipMemsetAsync(counts, 0, 64 * sizeof(int), stream);
    gate_v3<<<dim3(NTOK / 8), 256, 0, stream>>>(x, gw, gb, logits, xbf);
    topk_kernel<<<dim3(NTOK / 256), 256, 0, stream>>>(logits, counts, lists, wlists);
    scan_v3<<<1, 128, 0, stream>>>(counts, hbase_g, tableA, tableR0, tableR1, tns);
    conv_w1_v2<<<dim3(34, 80, 6), 256, 0, stream>>>(sw1, rw1, w1T);
    conv_w2_v2<<<dim3(33, 12, 80), 256, 0, stream>>>(sw2, rw2, w2sT, w2rT);
    ffn1_v3<<<dim3(320, 3), 256, 0, stream>>>(xbf, w1T, sb1, rb1, lists, counts,
                                              hbase_g, tableA, tns, hbuf);
    ffn2_shared_v2<<<dim3(32, 40), 256, 0, stream>>>(hbuf, w2sT, sb2, out);
    ffn2_routed_v2<<<dim3(128, 40), 256, 0, stream>>>(hbuf, w2rT, rb2, lists, wlists,
                                                      counts, hbase_g, tableR0, tns, 1, out);
    ffn2_routed_v2<<<dim3(128, 40), 256, 0, stream>>>(hbuf, w2rT, rb2, lists, wlists,
                                                      counts, hbase_g, tableR1, tns, 2, out);
    return;
  }

  // ---------------- fallback: round-1 proven path ----------------
  if (ws_size < WS_OLD) return;
  float* logits   = (float*)(ws + OFF_LOGITS);
  int* counts     = (int*)(ws + OFF_COUNTS);
  int* seg_count  = (int*)(ws + OFF_SEGC);
  int* seg_hbase  = (int*)(ws + OFF_SEGB);
  int2* tableA    = (int2*)(ws + OFF_TABA);
  int2* tableR0   = (int2*)(ws + OFF_TABR0);
  int2* tableR1   = (int2*)(ws + OFF_TABR1);
  int* tns        = (int*)(ws + OFF_TNS);
  int* lists      = (int*)(ws + OFF_LISTS);
  float* wlists   = (float*)(ws + OFF_WLISTS);
  unsigned short* hbuf = (unsigned short*)(ws + OFF_HBUF);

  hipMemsetAsync(counts, 0, 64 * sizeof(int), stream);
  gate_logits_kernel<<<dim3(NTOK / 16), 256, 0, stream>>>(x, gw, gb, logits, (unsigned short*)0);
  topk_kernel<<<dim3(NTOK / 256), 256, 0, stream>>>(logits, counts, lists, wlists);
  scan_kernel<<<1, 1, 0, stream>>>(counts, seg_count, seg_hbase, tableA, tableR0, tableR1, tns);
  ffn1_kernel<<<dim3(384, 6), 256, 0, stream>>>(x, sw1, sb1, rw1, rb1, lists,
                                                seg_count, seg_hbase, tableA, tns, hbuf);
  ffn2_shared_kernel<<<dim3(64, 80), 256, 0, stream>>>(hbuf, sw2, sb2, out);
  ffn2_routed_kernel<<<dim3(128, 80), 256, 0, stream>>>(hbuf, rw2, rb2, lists, wlists,
                                                        counts, seg_hbase, tableR0, tns, 1, out);
  ffn2_routed_kernel<<<dim3(128, 80), 256, 0, stream>>>(hbuf, rw2, rb2, lists, wlists,
                                                        counts, seg_hbase, tableR1, tns, 2, out);
}

// Round 7
// 646.034 us; speedup vs baseline: 1.0669x; 1.0669x over previous
//
#include <hip/hip_runtime.h>
#include <math.h>

// ---------------- problem constants ----------------
#define NTOK 4096      // B*T
#define DM   5120      // d_model
#define FD   384       // ffn_dim
#define NE   32        // routed experts

typedef float  f32x4  __attribute__((ext_vector_type(4)));
typedef __bf16 bf16x8 __attribute__((ext_vector_type(8)));
typedef unsigned short us2 __attribute__((ext_vector_type(2)));
typedef unsigned short us4 __attribute__((ext_vector_type(4)));
typedef unsigned short us8 __attribute__((ext_vector_type(8)));

__device__ __forceinline__ unsigned short f2bf(float f) {
  unsigned int u = __float_as_uint(f);
  u += 0x7fffu + ((u >> 16) & 1u);     // RNE
  return (unsigned short)(u >> 16);
}

__device__ __forceinline__ float gelu_f(float v) {
  return 0.5f * v * (1.0f + erff(v * 0.70710678118654752f));  // exact erf gelu
}

__device__ __forceinline__ bf16x8 ldf(const unsigned short* p) {
  us4 lo = *(const us4*)p;
  us4 hi = *(const us4*)(p + 4);
  us8 v = {lo[0], lo[1], lo[2], lo[3], hi[0], hi[1], hi[2], hi[3]};
  return __builtin_bit_cast(bf16x8, v);
}

__device__ __forceinline__ f32x4 mfma16(bf16x8 a, bf16x8 b, f32x4 c) {
  return __builtin_amdgcn_mfma_f32_16x16x32_bf16(a, b, c, 0, 0, 0);
}

// XOR-swizzled LDS tile read (tile row stride = 64 bf16 = 128B; g = 16B group)
__device__ __forceinline__ bf16x8 fragld(const unsigned short* t, int row, int g) {
  return *(const bf16x8*)(t + row * 64 + ((g ^ (row & 7)) << 3));
}
__device__ __forceinline__ void fragst(unsigned short* t, int row, int g, us8 v) {
  *(us8*)(t + row * 64 + ((g ^ (row & 7)) << 3)) = v;
}

// async global->LDS, 16B/lane. LDS dest = wave-uniform base + lane*16 (linear).
// Swizzle achieved by pre-swizzling the per-lane GLOBAL source (rule 21).
__device__ __forceinline__ void gld16(const void* g, void* l) {
  __builtin_amdgcn_global_load_lds(
      (const __attribute__((address_space(1))) unsigned int*)g,
      (__attribute__((address_space(3))) unsigned int*)l, 16, 0, 0);
}

// ================= OLD-PATH ws layout (fallback; 15.3 MB) =================
#define OFF_LOGITS 0
#define OFF_COUNTS 524288
#define OFF_SEGC   524800
#define OFF_SEGB   525312
#define OFF_TABA   525824
#define OFF_TABR0  528896
#define OFF_TABR1  529920
#define OFF_TNS    530944
#define OFF_LISTS  531456
#define OFF_WLISTS 1580032
#define OFF_HBUF   2628608
#define WS_OLD     15260672UL

// ================= NEW-PATH ws layout =================
#define L_LOGITS 0UL
#define L_COUNTS 524288UL
#define L_HBASE  524544UL
#define L_TABA   524800UL
#define L_TABR0  527360UL
#define L_TABR1  528384UL
#define L_TNS    529408UL
#define L_LISTS  529536UL
#define L_WLIST  1578112UL
#define L_HBUF   2626688UL
#define L_XBF    15258752UL
#define L_W1T    57201792UL
#define L_W2ST   190895232UL
#define L_W2RT   198759552UL
#define WS_NEW   324588672UL

// ---------------- gate v3: fp64-accurate logits + x->bf16 fold ----------------
__global__ __launch_bounds__(256) void gate_v3(
    const float* __restrict__ x, const float* __restrict__ gw,
    const float* __restrict__ gb, float* __restrict__ logits,
    unsigned short* __restrict__ xbf)
{
  __shared__ __align__(16) char gsm[22656];
  float*  xs = (float*)gsm;              // [8][132] f32
  float*  gs = (float*)(gsm + 4224);     // [128][36] f32
  double* ps = (double*)(gsm + 4224);    // [8][8][32] f64, reused after K loop

  int tid = threadIdx.x;
  int t0 = blockIdx.x * 8;

  int col  = tid & 15;
  int row  = (tid >> 4) & 1;
  int part = tid >> 5;
  int e0 = col * 2;

  double a[4][2];
  #pragma unroll
  for (int i = 0; i < 4; ++i) { a[i][0] = 0.0; a[i][1] = 0.0; }

  int sx_r = tid >> 5;
  int sx_c = (tid & 31) * 4;
  const float* xg = x + (size_t)(t0 + sx_r) * DM + sx_c;
  unsigned short* xo = xbf + (size_t)(t0 + sx_r) * DM + sx_c;

  for (int k0 = 0; k0 < DM; k0 += 128) {
    float4 xv4 = *(const float4*)(xg + k0);
    *(float4*)&xs[sx_r * 132 + sx_c] = xv4;
    us4 hx = {f2bf(xv4.x), f2bf(xv4.y), f2bf(xv4.z), f2bf(xv4.w)};
    *(us4*)(xo + k0) = hx;
    #pragma unroll
    for (int p = 0; p < 4; ++p) {
      int idx = p * 256 + tid;
      int r = idx >> 3, q = (idx & 7) * 4;
      float4 g4 = *(const float4*)(gw + (size_t)(k0 + r) * NE + q);
      *(float4*)&gs[r * 36 + q] = g4;
    }
    __syncthreads();
    #pragma unroll
    for (int kk = 0; kk < 16; ++kk) {
      int k = part * 16 + kk;
      double g0 = (double)gs[k * 36 + e0];
      double g1 = (double)gs[k * 36 + e0 + 1];
      #pragma unroll
      for (int i = 0; i < 4; ++i) {
        double xv = (double)xs[(row * 4 + i) * 132 + k];
        a[i][0] = fma(xv, g0, a[i][0]);
        a[i][1] = fma(xv, g1, a[i][1]);
      }
    }
    __syncthreads();
  }

  #pragma unroll
  for (int i = 0; i < 4; ++i) {
    double2 v; v.x = a[i][0]; v.y = a[i][1];
    *(double2*)&ps[(size_t)part * 256 + (row * 4 + i) * 32 + e0] = v;
  }
  __syncthreads();
  {
    int t = tid >> 5, e = tid & 31;
    double s = 0.0;
    #pragma unroll
    for (int p = 0; p < 8; ++p) s += ps[(size_t)p * 256 + t * 32 + e];
    logits[(size_t)(t0 + t) * NE + e] = (float)s + gb[e];
  }
}

// ---------------- old gate (fallback path only) ----------------
__global__ __launch_bounds__(256) void gate_logits_kernel(
    const float* __restrict__ x, const float* __restrict__ gw,
    const float* __restrict__ gb, float* __restrict__ logits,
    unsigned short* __restrict__ xbf)
{
  __shared__ float xs[16][33];
  __shared__ float gs[32][33];
  int tid = threadIdx.x;
  int t0 = blockIdx.x * 16;
  int r = tid >> 4;
  int e0 = (tid & 15) * 2;
  double a0 = 0.0, a1 = 0.0;
  for (int k0 = 0; k0 < DM; k0 += 32) {
    {
      int rr = tid >> 4, cc = (tid & 15) * 2;
      const float* s = x + (size_t)(t0 + rr) * DM + k0 + cc;
      float s0 = s[0], s1 = s[1];
      xs[rr][cc] = s0; xs[rr][cc + 1] = s1;
      if (xbf) {
        us2 h = {f2bf(s0), f2bf(s1)};
        *(us2*)(xbf + (size_t)(t0 + rr) * DM + k0 + cc) = h;
      }
    }
    {
      int rr = tid >> 3, cc = (tid & 7) * 4;
      float4 v = *(const float4*)(gw + (size_t)(k0 + rr) * NE + cc);
      gs[rr][cc] = v.x; gs[rr][cc + 1] = v.y; gs[rr][cc + 2] = v.z; gs[rr][cc + 3] = v.w;
    }
    __syncthreads();
    #pragma unroll
    for (int kk = 0; kk < 32; ++kk) {
      double a = (double)xs[r][kk];
      a0 += a * (double)gs[kk][e0];
      a1 += a * (double)gs[kk][e0 + 1];
    }
    __syncthreads();
  }
  logits[(size_t)(t0 + r) * NE + e0]     = (float)a0 + gb[e0];
  logits[(size_t)(t0 + r) * NE + e0 + 1] = (float)a1 + gb[e0 + 1];
}

// ---------------- softmax + top2 + scatter ----------------
__global__ void topk_kernel(const float* __restrict__ logits, int* __restrict__ counts,
                            int* __restrict__ lists, float* __restrict__ wlists)
{
  int t = blockIdx.x * blockDim.x + threadIdx.x;
  if (t >= NTOK) return;
  float l[32];
  const float4* lp = (const float4*)(logits + (size_t)t * NE);
  #pragma unroll
  for (int i = 0; i < 8; ++i) {
    float4 v = lp[i];
    l[i*4] = v.x; l[i*4+1] = v.y; l[i*4+2] = v.z; l[i*4+3] = v.w;
  }
  float mx = l[0];
  #pragma unroll
  for (int e = 1; e < 32; ++e) mx = fmaxf(mx, l[e]);
  float s = 0.f;
  #pragma unroll
  for (int e = 0; e < 32; ++e) s += expf(l[e] - mx);
  int i1 = 0; float b1 = l[0];
  #pragma unroll
  for (int e = 1; e < 32; ++e) if (l[e] > b1) { b1 = l[e]; i1 = e; }
  int i2 = -1; float b2 = -3.4e38f;
  #pragma unroll
  for (int e = 0; e < 32; ++e) if (e != i1 && l[e] > b2) { b2 = l[e]; i2 = e; }
  float p1 = expf(b1 - mx) / s;
  float p2 = expf(b2 - mx) / s;
  int pos = atomicAdd(&counts[i1], 1);
  lists [(size_t)i1 * NTOK + pos] = t;
  wlists[(size_t)i1 * NTOK + pos] = p1;
  pos = atomicAdd(&counts[32 + i2], 1);
  lists [(size_t)(32 + i2) * NTOK + pos] = t;
  wlists[(size_t)(32 + i2) * NTOK + pos] = p2;
}

// ================================================================
// ======================= OLD PATH (fallback) =====================
// ================================================================
__global__ void scan_kernel(const int* __restrict__ counts, int* __restrict__ seg_count,
                            int* __restrict__ seg_hbase, int2* __restrict__ tableA,
                            int2* __restrict__ tableR0, int2* __restrict__ tableR1,
                            int* __restrict__ tns)
{
  if (threadIdx.x != 0 || blockIdx.x != 0) return;
  seg_count[0] = NTOK; seg_hbase[0] = 0;
  seg_count[1] = NTOK; seg_hbase[1] = NTOK;
  int base = 2 * NTOK;
  for (int li = 0; li < 64; ++li) {
    int c = counts[li];
    seg_count[2 + li] = c; seg_hbase[2 + li] = base; base += c;
  }
  int nA = 0;
  for (int s = 0; s < 66; ++s) {
    int c = seg_count[s];
    for (int m0 = 0; m0 < c; m0 += 64) { tableA[nA].x = s; tableA[nA].y = m0; ++nA; }
  }
  int nR0 = 0;
  for (int li = 0; li < 32; ++li)
    for (int m0 = 0; m0 < counts[li]; m0 += 64) { tableR0[nR0].x = li; tableR0[nR0].y = m0; ++nR0; }
  int nR1 = 0;
  for (int li = 32; li < 64; ++li)
    for (int m0 = 0; m0 < counts[li]; m0 += 64) { tableR1[nR1].x = li; tableR1[nR1].y = m0; ++nR1; }
  tns[0] = nA; tns[1] = nR0; tns[2] = nR1;
}

__global__ __launch_bounds__(256) void ffn1_kernel(
    const float* __restrict__ x,
    const float* __restrict__ sw1, const float* __restrict__ sb1,
    const float* __restrict__ rw1, const float* __restrict__ rb1,
    const int* __restrict__ lists,
    const int* __restrict__ seg_count, const int* __restrict__ seg_hbase,
    const int2* __restrict__ tableA, const int* __restrict__ tns,
    unsigned short* __restrict__ hbuf)
{
  if ((int)blockIdx.x >= tns[0]) return;
  int2 ent = tableA[blockIdx.x];
  int seg = ent.x, m0 = ent.y;
  int cnt = seg_count[seg];
  int hbase = seg_hbase[seg];
  int n0 = blockIdx.y * 64;
  const float *w1, *b1;
  if (seg < 2) { w1 = sw1 + (size_t)seg * DM * FD; b1 = sb1 + (size_t)seg * FD; }
  else { int e = (seg - 2) & 31; w1 = rw1 + (size_t)e * DM * FD; b1 = rb1 + (size_t)e * FD; }
  __shared__ int toks[64];
  __shared__ unsigned short As[64][44];
  __shared__ unsigned short Bs[64][44];
  int tid = threadIdx.x;
  if (tid < 64) {
    int i = m0 + tid;
    int tk = 0;
    if (i < cnt) tk = (seg < 2) ? i : lists[(size_t)(seg - 2) * NTOK + i];
    toks[tid] = tk;
  }
  __syncthreads();
  int lane = tid & 63, wave = tid >> 6;
  int wr = (wave >> 1) * 32, wc = (wave & 1) * 32;
  int l15 = lane & 15, kb = (lane >> 4) * 8;
  f32x4 zz = {0.f, 0.f, 0.f, 0.f};
  f32x4 acc[2][2];
  #pragma unroll
  for (int i = 0; i < 2; ++i)
    #pragma unroll
    for (int j = 0; j < 2; ++j) acc[i][j] = zz;
  int ar = tid >> 2, ac = (tid & 3) * 8;
  const float* axp = x + (size_t)toks[ar] * DM + ac;
  int br = tid >> 3, bc = (tid & 7) * 8;
  const float* bwp = w1 + (size_t)br * FD + n0 + bc;
  for (int k0 = 0; k0 < DM; k0 += 32) {
    float4 a0 = *(const float4*)(axp + k0);
    float4 a1 = *(const float4*)(axp + k0 + 4);
    float4 w0 = *(const float4*)bwp;
    float4 w4 = *(const float4*)(bwp + 4);
    bwp += (size_t)32 * FD;
    us4 pa0 = {f2bf(a0.x), f2bf(a0.y), f2bf(a0.z), f2bf(a0.w)};
    us4 pa1 = {f2bf(a1.x), f2bf(a1.y), f2bf(a1.z), f2bf(a1.w)};
    *(us4*)&As[ar][ac] = pa0;
    *(us4*)&As[ar][ac + 4] = pa1;
    Bs[bc + 0][br] = f2bf(w0.x); Bs[bc + 1][br] = f2bf(w0.y);
    Bs[bc + 2][br] = f2bf(w0.z); Bs[bc + 3][br] = f2bf(w0.w);
    Bs[bc + 4][br] = f2bf(w4.x); Bs[bc + 5][br] = f2bf(w4.y);
    Bs[bc + 6][br] = f2bf(w4.z); Bs[bc + 7][br] = f2bf(w4.w);
    __syncthreads();
    bf16x8 af0 = ldf(&As[wr + l15][kb]);
    bf16x8 af1 = ldf(&As[wr + 16 + l15][kb]);
    bf16x8 bf0 = ldf(&Bs[wc + l15][kb]);
    bf16x8 bf1 = ldf(&Bs[wc + 16 + l15][kb]);
    acc[0][0] = mfma16(af0, bf0, acc[0][0]);
    acc[0][1] = mfma16(af0, bf1, acc[0][1]);
    acc[1][0] = mfma16(af1, bf0, acc[1][0]);
    acc[1][1] = mfma16(af1, bf1, acc[1][1]);
    __syncthreads();
  }
  int rb4 = (lane >> 4) * 4;
  #pragma unroll
  for (int mi = 0; mi < 2; ++mi) {
    #pragma unroll
    for (int rg = 0; rg < 4; ++rg) {
      int gi = m0 + wr + mi * 16 + rb4 + rg;
      if (gi < cnt) {
        #pragma unroll
        for (int ni = 0; ni < 2; ++ni) {
          int ncol = n0 + wc + ni * 16 + l15;
          float v = acc[mi][ni][rg] + b1[ncol];
          hbuf[(size_t)(hbase + gi) * FD + ncol] = f2bf(gelu_f(v));
        }
      }
    }
  }
}

__global__ __launch_bounds__(256) void ffn2_shared_kernel(
    const unsigned short* __restrict__ hbuf,
    const float* __restrict__ sw2, const float* __restrict__ sb2,
    float* __restrict__ out)
{
  int m0 = blockIdx.x * 64;
  int n0 = blockIdx.y * 64;
  __shared__ unsigned short As[64][44];
  __shared__ unsigned short Bs[64][44];
  int tid = threadIdx.x;
  int lane = tid & 63, wave = tid >> 6;
  int wr = (wave >> 1) * 32, wc = (wave & 1) * 32;
  int l15 = lane & 15, kb = (lane >> 4) * 8;
  f32x4 zz = {0.f, 0.f, 0.f, 0.f};
  f32x4 acc[2][2];
  #pragma unroll
  for (int i = 0; i < 2; ++i)
    #pragma unroll
    for (int j = 0; j < 2; ++j) acc[i][j] = zz;
  int ar = tid >> 2, ac = (tid & 3) * 8;
  int br = tid >> 3, bc = (tid & 7) * 8;
  const float* bwp = sw2 + (size_t)br * DM + n0 + bc;
  for (int k0 = 0; k0 < 2 * FD; k0 += 32) {
    int side = (k0 >= FD) ? 1 : 0;
    const unsigned short* ap =
        hbuf + (size_t)(side * NTOK + m0 + ar) * FD + (k0 - side * FD) + ac;
    us8 av = *(const us8*)ap;
    float4 w0 = *(const float4*)bwp;
    float4 w4 = *(const float4*)(bwp + 4);
    bwp += (size_t)32 * DM;
    us4 alo = {av[0], av[1], av[2], av[3]};
    us4 ahi = {av[4], av[5], av[6], av[7]};
    *(us4*)&As[ar][ac] = alo;
    *(us4*)&As[ar][ac + 4] = ahi;
    Bs[bc + 0][br] = f2bf(w0.x); Bs[bc + 1][br] = f2bf(w0.y);
    Bs[bc + 2][br] = f2bf(w0.z); Bs[bc + 3][br] = f2bf(w0.w);
    Bs[bc + 4][br] = f2bf(w4.x); Bs[bc + 5][br] = f2bf(w4.y);
    Bs[bc + 6][br] = f2bf(w4.z); Bs[bc + 7][br] = f2bf(w4.w);
    __syncthreads();
    bf16x8 af0 = ldf(&As[wr + l15][kb]);
    bf16x8 af1 = ldf(&As[wr + 16 + l15][kb]);
    bf16x8 bf0 = ldf(&Bs[wc + l15][kb]);
    bf16x8 bf1 = ldf(&Bs[wc + 16 + l15][kb]);
    acc[0][0] = mfma16(af0, bf0, acc[0][0]);
    acc[0][1] = mfma16(af0, bf1, acc[0][1]);
    acc[1][0] = mfma16(af1, bf0, acc[1][0]);
    acc[1][1] = mfma16(af1, bf1, acc[1][1]);
    __syncthreads();
  }
  int rb4 = (lane >> 4) * 4;
  #pragma unroll
  for (int mi = 0; mi < 2; ++mi) {
    #pragma unroll
    for (int rg = 0; rg < 4; ++rg) {
      int row = m0 + wr + mi * 16 + rb4 + rg;
      #pragma unroll
      for (int ni = 0; ni < 2; ++ni) {
        int ncol = n0 + wc + ni * 16 + l15;
        out[(size_t)row * DM + ncol] = acc[mi][ni][rg] + sb2[ncol] + sb2[DM + ncol];
      }
    }
  }
}

__global__ __launch_bounds__(256) void ffn2_routed_kernel(
    const unsigned short* __restrict__ hbuf,
    const float* __restrict__ rw2, const float* __restrict__ rb2,
    const int* __restrict__ lists, const float* __restrict__ wlists,
    const int* __restrict__ counts, const int* __restrict__ seg_hbase,
    const int2* __restrict__ tableR, const int* __restrict__ tns, int tidx,
    float* __restrict__ out)
{
  if ((int)blockIdx.x >= tns[tidx]) return;
  int2 ent = tableR[blockIdx.x];
  int li = ent.x, m0 = ent.y;
  int cnt = counts[li];
  int hbase = seg_hbase[2 + li];
  int e = li & 31;
  int n0 = blockIdx.y * 64;
  const float* w2 = rw2 + (size_t)e * FD * DM;
  const float* b2 = rb2 + (size_t)e * DM;
  __shared__ unsigned short As[64][44];
  __shared__ unsigned short Bs[64][44];
  int tid = threadIdx.x;
  int lane = tid & 63, wave = tid >> 6;
  int wr = (wave >> 1) * 32, wc = (wave & 1) * 32;
  int l15 = lane & 15, kb = (lane >> 4) * 8;
  f32x4 zz = {0.f, 0.f, 0.f, 0.f};
  f32x4 acc[2][2];
  #pragma unroll
  for (int i = 0; i < 2; ++i)
    #pragma unroll
    for (int j = 0; j < 2; ++j) acc[i][j] = zz;
  int ar = tid >> 2, ac = (tid & 3) * 8;
  const unsigned short* ap = hbuf + (size_t)(hbase + m0 + ar) * FD + ac;
  int br = tid >> 3, bc = (tid & 7) * 8;
  const float* bwp = w2 + (size_t)br * DM + n0 + bc;
  for (int k0 = 0; k0 < FD; k0 += 32) {
    us8 av = *(const us8*)(ap + k0);
    float4 w0 = *(const float4*)bwp;
    float4 w4 = *(const float4*)(bwp + 4);
    bwp += (size_t)32 * DM;
    us4 alo = {av[0], av[1], av[2], av[3]};
    us4 ahi = {av[4], av[5], av[6], av[7]};
    *(us4*)&As[ar][ac] = alo;
    *(us4*)&As[ar][ac + 4] = ahi;
    Bs[bc + 0][br] = f2bf(w0.x); Bs[bc + 1][br] = f2bf(w0.y);
    Bs[bc + 2][br] = f2bf(w0.z); Bs[bc + 3][br] = f2bf(w0.w);
    Bs[bc + 4][br] = f2bf(w4.x); Bs[bc + 5][br] = f2bf(w4.y);
    Bs[bc + 6][br] = f2bf(w4.z); Bs[bc + 7][br] = f2bf(w4.w);
    __syncthreads();
    bf16x8 af0 = ldf(&As[wr + l15][kb]);
    bf16x8 af1 = ldf(&As[wr + 16 + l15][kb]);
    bf16x8 bf0 = ldf(&Bs[wc + l15][kb]);
    bf16x8 bf1 = ldf(&Bs[wc + 16 + l15][kb]);
    acc[0][0] = mfma16(af0, bf0, acc[0][0]);
    acc[0][1] = mfma16(af0, bf1, acc[0][1]);
    acc[1][0] = mfma16(af1, bf0, acc[1][0]);
    acc[1][1] = mfma16(af1, bf1, acc[1][1]);
    __syncthreads();
  }
  int rb4 = (lane >> 4) * 4;
  #pragma unroll
  for (int mi = 0; mi < 2; ++mi) {
    #pragma unroll
    for (int rg = 0; rg < 4; ++rg) {
      int gi = m0 + wr + mi * 16 + rb4 + rg;
      if (gi < cnt) {
        int tok = lists[(size_t)li * NTOK + gi];
        float wgt = wlists[(size_t)li * NTOK + gi];
        #pragma unroll
        for (int ni = 0; ni < 2; ++ni) {
          int ncol = n0 + wc + ni * 16 + l15;
          float v = (acc[mi][ni][rg] + b2[ncol]) * wgt;
          out[(size_t)tok * DM + ncol] += v;
        }
      }
    }
  }
}

// ================================================================
// ========================= NEW PATH =============================
// ================================================================

// table builder
__global__ void scan_v3(const int* __restrict__ counts, int* __restrict__ hbase_g,
                        int2* __restrict__ tableA, int2* __restrict__ tableR0,
                        int2* __restrict__ tableR1, int* __restrict__ tns)
{
  __shared__ int cnt[64], tprefA[64], tpref0[32], tpref1[32], hpref[64];
  int t = threadIdx.x;
  if (t < 64) cnt[t] = counts[t];
  __syncthreads();
  if (t == 0) {
    int hb = 2 * NTOK, ta = 128, t0 = 0, t1 = 0;
    for (int i = 0; i < 64; ++i) {
      int nt = (cnt[i] + 63) >> 6;
      hpref[i] = hb; hb += cnt[i];
      tprefA[i] = ta; ta += nt;
      if (i < 32) { tpref0[i] = t0; t0 += nt; }
      else        { tpref1[i - 32] = t1; t1 += nt; }
    }
    tns[0] = ta; tns[1] = t0; tns[2] = t1;
  }
  __syncthreads();
  if (t < 128) {
    int2 ent; ent.x = t >> 6; ent.y = (t & 63) * 64;
    tableA[t] = ent;
  }
  if (t < 64) {
    hbase_g[t] = hpref[t];
    int nt = (cnt[t] + 63) >> 6;
    for (int j = 0; j < nt; ++j) {
      int2 ent; ent.x = 2 + t; ent.y = j * 64;
      tableA[tprefA[t] + j] = ent;
      int2 entR; entR.x = t; entR.y = j * 64;
      if (t < 32) tableR0[tpref0[t] + j] = entR;
      else        tableR1[tpref1[t - 32] + j] = entR;
    }
  }
}

// transpose-convert w1 f32 [seg][k][n] -> bf16 [seg][n][k]
// LDS swizzle: element (row,c) at col c ^ (((row>>4)&3)<<4); float4 alignment kept.
__global__ __launch_bounds__(256) void conv_w1_v2(
    const float* __restrict__ sw1, const float* __restrict__ rw1,
    unsigned short* __restrict__ w1T)
{
  int seg = blockIdx.x;
  int k0 = blockIdx.y * 64;
  int n0 = blockIdx.z * 64;
  const float* src = (seg < 2) ? sw1 + (size_t)seg * DM * FD
                               : rw1 + (size_t)(seg - 2) * DM * FD;
  __shared__ float ls[64][68];
  int tid = threadIdx.x;
  int r = tid >> 4, c4 = (tid & 15) * 4;
  #pragma unroll
  for (int p = 0; p < 4; ++p) {
    int row = r + p * 16;
    float4 v = *(const float4*)(src + (size_t)(k0 + row) * FD + n0 + c4);
    *(float4*)&ls[row][c4 ^ (((row >> 4) & 3) << 4)] = v;
  }
  __syncthreads();
  int n = tid >> 2, kseg = (tid & 3) * 16;
  int swz = ((kseg >> 4) & 3) << 4;
  unsigned short tmp[16];
  #pragma unroll
  for (int j = 0; j < 16; ++j) tmp[j] = f2bf(ls[kseg + j][n ^ swz]);
  unsigned short* dst = w1T + (size_t)seg * FD * DM + (size_t)(n0 + n) * DM + k0 + kseg;
  us8 o0 = {tmp[0], tmp[1], tmp[2], tmp[3], tmp[4], tmp[5], tmp[6], tmp[7]};
  us8 o1 = {tmp[8], tmp[9], tmp[10], tmp[11], tmp[12], tmp[13], tmp[14], tmp[15]};
  *(us8*)dst = o0;
  *(us8*)(dst + 8) = o1;
}

// transpose-convert w2 (same swizzle)
__global__ __launch_bounds__(256) void conv_w2_v2(
    const float* __restrict__ sw2, const float* __restrict__ rw2,
    unsigned short* __restrict__ w2sT, unsigned short* __restrict__ w2rT)
{
  int e = blockIdx.x;
  int K = (e == 0) ? 2 * FD : FD;
  int k0 = blockIdx.y * 64;
  if (k0 >= K) return;
  int n0 = blockIdx.z * 64;
  const float* src = (e == 0) ? sw2 : rw2 + (size_t)(e - 1) * FD * DM;
  unsigned short* dstb = (e == 0) ? w2sT : w2rT + (size_t)(e - 1) * DM * FD;
  __shared__ float ls[64][68];
  int tid = threadIdx.x;
  int r = tid >> 4, c4 = (tid & 15) * 4;
  #pragma unroll
  for (int p = 0; p < 4; ++p) {
    int row = r + p * 16;
    float4 v = *(const float4*)(src + (size_t)(k0 + row) * DM + n0 + c4);
    *(float4*)&ls[row][c4 ^ (((row >> 4) & 3) << 4)] = v;
  }
  __syncthreads();
  int n = tid >> 2, kseg = (tid & 3) * 16;
  int swz = ((kseg >> 4) & 3) << 4;
  unsigned short tmp[16];
  #pragma unroll
  for (int j = 0; j < 16; ++j) tmp[j] = f2bf(ls[kseg + j][n ^ swz]);
  unsigned short* dst = dstb + (size_t)(n0 + n) * K + k0 + kseg;
  us8 o0 = {tmp[0], tmp[1], tmp[2], tmp[3], tmp[4], tmp[5], tmp[6], tmp[7]};
  us8 o1 = {tmp[8], tmp[9], tmp[10], tmp[11], tmp[12], tmp[13], tmp[14], tmp[15]};
  *(us8*)dst = o0;
  *(us8*)(dst + 8) = o1;
}

// unified ffn1: 64x128 tiles, K=5120, single-buffer LDS + global_load_lds staging.
// LDS dest linear (wave-uniform base + lane*16); source pre-swizzled (rule 21).
__global__ __launch_bounds__(256) void ffn1_v3(
    const unsigned short* __restrict__ xbf, const unsigned short* __restrict__ w1T,
    const float* __restrict__ sb1, const float* __restrict__ rb1,
    const int* __restrict__ lists, const int* __restrict__ counts,
    const int* __restrict__ hbase_g, const int2* __restrict__ tableA,
    const int* __restrict__ tns, unsigned short* __restrict__ hbuf)
{
  if ((int)blockIdx.x >= tns[0]) return;
  int2 ent = tableA[blockIdx.x];
  int seg = ent.x, m0 = ent.y;
  int cnt, hbase, wseg;
  const float* b1;
  if (seg < 2) {
    cnt = NTOK; hbase = seg * NTOK; b1 = sb1 + seg * FD; wseg = seg;
  } else {
    int li = seg - 2;
    int e = li & 31;
    cnt = counts[li]; hbase = hbase_g[li];
    b1 = rb1 + (size_t)e * FD;
    wseg = 2 + e;
  }
  int n0 = blockIdx.y * 128;
  const unsigned short* w1 = w1T + (size_t)wseg * FD * DM;

  __shared__ int toks[64];
  __shared__ __align__(16) unsigned short As[64 * 64];
  __shared__ __align__(16) unsigned short Bs[128 * 64];

  int tid = threadIdx.x;
  if (tid < 64) {
    int i = m0 + tid;
    int tk;
    if (seg < 2) tk = (i < cnt) ? i : 0;
    else tk = (i < cnt) ? lists[(size_t)(seg - 2) * NTOK + i] : 0;
    toks[tid] = tk;
  }
  __syncthreads();

  int lane = tid & 63, wave = tid >> 6;
  int wr = (wave >> 1) * 32, wc = (wave & 1) * 64;
  int l15 = lane & 15, l4 = lane >> 4;

  f32x4 zz = {0.f, 0.f, 0.f, 0.f};
  f32x4 acc[2][4];
  #pragma unroll
  for (int i = 0; i < 2; ++i)
    #pragma unroll
    for (int j = 0; j < 4; ++j) acc[i][j] = zz;

  // per-lane staging geometry: chunk = 8 rows (1KB); g = lane&7, localrow = lane>>3
  int g = lane & 7, lr = lane >> 3;
  // A: 2 chunks/wave -> rows wave*16 + p*8 + lr
  int arow[2];  const unsigned short* agsrc[2];  unsigned short* aldst[2];
  #pragma unroll
  for (int p = 0; p < 2; ++p) {
    arow[p] = wave * 16 + p * 8 + lr;
    agsrc[p] = xbf + (size_t)toks[arow[p]] * DM + ((g ^ (arow[p] & 7)) << 3);
    aldst[p] = As + (wave * 16 + p * 8) * 64;   // wave-uniform
  }
  // B: 4 chunks/wave -> rows wave*32 + p*8 + lr
  int brow[4];  const unsigned short* bgsrc[4];  unsigned short* bldst[4];
  #pragma unroll
  for (int p = 0; p < 4; ++p) {
    brow[p] = wave * 32 + p * 8 + lr;
    bgsrc[p] = w1 + (size_t)(n0 + brow[p]) * DM + ((g ^ (brow[p] & 7)) << 3);
    bldst[p] = Bs + (wave * 32 + p * 8) * 64;   // wave-uniform
  }

  for (int k0 = 0; k0 < DM; k0 += 64) {
    #pragma unroll
    for (int p = 0; p < 2; ++p) gld16(agsrc[p] + k0, aldst[p]);
    #pragma unroll
    for (int p = 0; p < 4; ++p) gld16(bgsrc[p] + k0, bldst[p]);
    __syncthreads();                    // drains vmcnt; tile visible
    #pragma unroll
    for (int kk = 0; kk < 2; ++kk) {
      bf16x8 af[2], bfr[4];
      #pragma unroll
      for (int mi = 0; mi < 2; ++mi) af[mi] = fragld(As, wr + mi * 16 + l15, kk * 4 + l4);
      #pragma unroll
      for (int ni = 0; ni < 4; ++ni) bfr[ni] = fragld(Bs, wc + ni * 16 + l15, kk * 4 + l4);
      #pragma unroll
      for (int mi = 0; mi < 2; ++mi)
        #pragma unroll
        for (int ni = 0; ni < 4; ++ni) acc[mi][ni] = mfma16(af[mi], bfr[ni], acc[mi][ni]);
    }
    __syncthreads();                    // all reads done before next-stage writes
  }

  int rb4 = l4 * 4;
  #pragma unroll
  for (int mi = 0; mi < 2; ++mi) {
    #pragma unroll
    for (int rg = 0; rg < 4; ++rg) {
      int gi = m0 + wr + mi * 16 + rb4 + rg;
      if (gi < cnt) {
        #pragma unroll
        for (int ni = 0; ni < 4; ++ni) {
          int ncol = n0 + wc + ni * 16 + l15;
          float v = acc[mi][ni][rg] + b1[ncol];
          hbuf[(size_t)(hbase + gi) * FD + ncol] = f2bf(gelu_f(v));
        }
      }
    }
  }
}

// ffn2 shared: dense 128x128, K=768, global_load_lds staging
__global__ __launch_bounds__(256) void ffn2_shared_v2(
    const unsigned short* __restrict__ hbuf, const unsigned short* __restrict__ w2sT,
    const float* __restrict__ sb2, float* __restrict__ out)
{
  int m0 = blockIdx.x * 128;
  int n0 = blockIdx.y * 128;

  __shared__ __align__(16) unsigned short As[128 * 64];
  __shared__ __align__(16) unsigned short Bs[128 * 64];

  int tid = threadIdx.x;
  int lane = tid & 63, wave = tid >> 6;
  int wr = (wave >> 1) * 64, wc = (wave & 1) * 64;
  int l15 = lane & 15, l4 = lane >> 4;

  f32x4 zz = {0.f, 0.f, 0.f, 0.f};
  f32x4 acc[4][4];
  #pragma unroll
  for (int i = 0; i < 4; ++i)
    #pragma unroll
    for (int j = 0; j < 4; ++j) acc[i][j] = zz;

  int g = lane & 7, lr = lane >> 3;
  int prow[4];  unsigned short* aldst[4];  unsigned short* bldst[4];
  const unsigned short* bgsrc[4];
  int aswz[4];
  #pragma unroll
  for (int p = 0; p < 4; ++p) {
    prow[p] = wave * 32 + p * 8 + lr;
    aldst[p] = As + (wave * 32 + p * 8) * 64;
    bldst[p] = Bs + (wave * 32 + p * 8) * 64;
    aswz[p] = (g ^ (prow[p] & 7)) << 3;
    bgsrc[p] = w2sT + (size_t)(n0 + prow[p]) * (2 * FD) + aswz[p];
  }

  for (int k0 = 0; k0 < 2 * FD; k0 += 64) {
    int side = (k0 >= FD) ? 1 : 0;
    int kk0 = k0 - side * FD;
    #pragma unroll
    for (int p = 0; p < 4; ++p)
      gld16(hbuf + (size_t)(side * NTOK + m0 + prow[p]) * FD + kk0 + aswz[p], aldst[p]);
    #pragma unroll
    for (int p = 0; p < 4; ++p) gld16(bgsrc[p] + k0, bldst[p]);
    __syncthreads();
    #pragma unroll
    for (int kk = 0; kk < 2; ++kk) {
      bf16x8 af[4], bfr[4];
      #pragma unroll
      for (int mi = 0; mi < 4; ++mi) af[mi] = fragld(As, wr + mi * 16 + l15, kk * 4 + l4);
      #pragma unroll
      for (int ni = 0; ni < 4; ++ni) bfr[ni] = fragld(Bs, wc + ni * 16 + l15, kk * 4 + l4);
      #pragma unroll
      for (int mi = 0; mi < 4; ++mi)
        #pragma unroll
        for (int ni = 0; ni < 4; ++ni) acc[mi][ni] = mfma16(af[mi], bfr[ni], acc[mi][ni]);
    }
    __syncthreads();
  }

  int rb4 = l4 * 4;
  #pragma unroll
  for (int mi = 0; mi < 4; ++mi) {
    #pragma unroll
    for (int rg = 0; rg < 4; ++rg) {
      int row = m0 + wr + mi * 16 + rb4 + rg;
      #pragma unroll
      for (int ni = 0; ni < 4; ++ni) {
        int ncol = n0 + wc + ni * 16 + l15;
        out[(size_t)row * DM + ncol] = acc[mi][ni][rg] + sb2[ncol] + sb2[DM + ncol];
      }
    }
  }
}

// ffn2 routed: 64x128, K=384, global_load_lds staging, out += w*(h@w2+b2)
__global__ __launch_bounds__(256) void ffn2_routed_v2(
    const unsigned short* __restrict__ hbuf, const unsigned short* __restrict__ w2rT,
    const float* __restrict__ rb2, const int* __restrict__ lists,
    const float* __restrict__ wlists, const int* __restrict__ counts,
    const int* __restrict__ hbase_g, const int2* __restrict__ tableR,
    const int* __restrict__ tns, int tidx, float* __restrict__ out)
{
  if ((int)blockIdx.x >= tns[tidx]) return;
  int2 ent = tableR[blockIdx.x];
  int li = ent.x, m0 = ent.y;
  int cnt = counts[li];
  int hbase = hbase_g[li];
  int e = li & 31;
  int n0 = blockIdx.y * 128;
  const unsigned short* w2 = w2rT + (size_t)e * DM * FD;

  __shared__ __align__(16) unsigned short As[64 * 64];
  __shared__ __align__(16) unsigned short Bs[128 * 64];

  int tid = threadIdx.x;
  int lane = tid & 63, wave = tid >> 6;
  int wr = (wave >> 1) * 32, wc = (wave & 1) * 64;
  int l15 = lane & 15, l4 = lane >> 4;

  f32x4 zz = {0.f, 0.f, 0.f, 0.f};
  f32x4 acc[2][4];
  #pragma unroll
  for (int i = 0; i < 2; ++i)
    #pragma unroll
    for (int j = 0; j < 4; ++j) acc[i][j] = zz;

  int g = lane & 7, lr = lane >> 3;
  const unsigned short* agsrc[2];  unsigned short* aldst[2];
  #pragma unroll
  for (int p = 0; p < 2; ++p) {
    int arow = wave * 16 + p * 8 + lr;
    agsrc[p] = hbuf + (size_t)(hbase + m0 + arow) * FD + ((g ^ (arow & 7)) << 3);
    aldst[p] = As + (wave * 16 + p * 8) * 64;
  }
  const unsigned short* bgsrc[4];  unsigned short* bldst[4];
  #pragma unroll
  for (int p = 0; p < 4; ++p) {
    int brow = wave * 32 + p * 8 + lr;
    bgsrc[p] = w2 + (size_t)(n0 + brow) * FD + ((g ^ (brow & 7)) << 3);
    bldst[p] = Bs + (wave * 32 + p * 8) * 64;
  }

  for (int k0 = 0; k0 < FD; k0 += 64) {
    #pragma unroll
    for (int p = 0; p < 2; ++p) gld16(agsrc[p] + k0, aldst[p]);
    #pragma unroll
    for (int p = 0; p < 4; ++p) gld16(bgsrc[p] + k0, bldst[p]);
    __syncthreads();
    #pragma unroll
    for (int kk = 0; kk < 2; ++kk) {
      bf16x8 af[2], bfr[4];
      #pragma unroll
      for (int mi = 0; mi < 2; ++mi) af[mi] = fragld(As, wr + mi * 16 + l15, kk * 4 + l4);
      #pragma unroll
      for (int ni = 0; ni < 4; ++ni) bfr[ni] = fragld(Bs, wc + ni * 16 + l15, kk * 4 + l4);
      #pragma unroll
      for (int mi = 0; mi < 2; ++mi)
        #pragma unroll
        for (int ni = 0; ni < 4; ++ni) acc[mi][ni] = mfma16(af[mi], bfr[ni], acc[mi][ni]);
    }
    __syncthreads();
  }

  int rb4 = l4 * 4;
  #pragma unroll
  for (int mi = 0; mi < 2; ++mi) {
    #pragma unroll
    for (int rg = 0; rg < 4; ++rg) {
      int gi = m0 + wr + mi * 16 + rb4 + rg;
      if (gi < cnt) {
        int tok = lists[(size_t)li * NTOK + gi];
        float wgt = wlists[(size_t)li * NTOK + gi];
        #pragma unroll
        for (int ni = 0; ni < 4; ++ni) {
          int ncol = n0 + wc + ni * 16 + l15;
          float v = (acc[mi][ni][rg] + rb2[(size_t)e * DM + ncol]) * wgt;
          out[(size_t)tok * DM + ncol] += v;
        }
      }
    }
  }
}

// ---------------- launch ----------------
extern "C" void kernel_launch(void* const* d_in, const int* in_sizes, int n_in,
                              void* d_out, int out_size, void* d_ws, size_t ws_size,
                              hipStream_t stream) {
  const float* x   = (const float*)d_in[0];
  const float* sw1 = (const float*)d_in[1];
  const float* sb1 = (const float*)d_in[2];
  const float* sw2 = (const float*)d_in[3];
  const float* sb2 = (const float*)d_in[4];
  const float* rw1 = (const float*)d_in[5];
  const float* rb1 = (const float*)d_in[6];
  const float* rw2 = (const float*)d_in[7];
  const float* rb2 = (const float*)d_in[8];
  const float* gw  = (const float*)d_in[9];
  const float* gb  = (const float*)d_in[10];
  float* out = (float*)d_out;
  char* ws = (char*)d_ws;

  if (ws_size >= WS_NEW) {
    float* logits  = (float*)(ws + L_LOGITS);
    int* counts    = (int*)(ws + L_COUNTS);
    int* hbase_g   = (int*)(ws + L_HBASE);
    int2* tableA   = (int2*)(ws + L_TABA);
    int2* tableR0  = (int2*)(ws + L_TABR0);
    int2* tableR1  = (int2*)(ws + L_TABR1);
    int* tns       = (int*)(ws + L_TNS);
    int* lists     = (int*)(ws + L_LISTS);
    float* wlists  = (float*)(ws + L_WLIST);
    unsigned short* hbuf = (unsigned short*)(ws + L_HBUF);
    unsigned short* xbf  = (unsigned short*)(ws + L_XBF);
    unsigned short* w1T  = (unsigned short*)(ws + L_W1T);
    unsigned short* w2sT = (unsigned short*)(ws + L_W2ST);
    unsigned short* w2rT = (unsigned short*)(ws + L_W2RT);

    hipMemsetAsync(counts, 0, 64 * sizeof(int), stream);
    gate_v3<<<dim3(NTOK / 8), 256, 0, stream>>>(x, gw, gb, logits, xbf);
    topk_kernel<<<dim3(NTOK / 256), 256, 0, stream>>>(logits, counts, lists, wlists);
    scan_v3<<<1, 128, 0, stream>>>(counts, hbase_g, tableA, tableR0, tableR1, tns);
    conv_w1_v2<<<dim3(34, 80, 6), 256, 0, stream>>>(sw1, rw1, w1T);
    conv_w2_v2<<<dim3(33, 12, 80), 256, 0, stream>>>(sw2, rw2, w2sT, w2rT);
    ffn1_v3<<<dim3(320, 3), 256, 0, stream>>>(xbf, w1T, sb1, rb1, lists, counts,
                                              hbase_g, tableA, tns, hbuf);
    ffn2_shared_v2<<<dim3(32, 40), 256, 0, stream>>>(hbuf, w2sT, sb2, out);
    ffn2_routed_v2<<<dim3(128, 40), 256, 0, stream>>>(hbuf, w2rT, rb2, lists, wlists,
                                                      counts, hbase_g, tableR0, tns, 1, out);
    ffn2_routed_v2<<<dim3(128, 40), 256, 0, stream>>>(hbuf, w2rT, rb2, lists, wlists,
                                                      counts, hbase_g, tableR1, tns, 2, out);
    return;
  }

  // ---------------- fallback: round-1 proven path ----------------
  if (ws_size < WS_OLD) return;
  float* logits   = (float*)(ws + OFF_LOGITS);
  int* counts     = (int*)(ws + OFF_COUNTS);
  int* seg_count  = (int*)(ws + OFF_SEGC);
  int* seg_hbase  = (int*)(ws + OFF_SEGB);
  int2* tableA    = (int2*)(ws + OFF_TABA);
  int2* tableR0   = (int2*)(ws + OFF_TABR0);
  int2* tableR1   = (int2*)(ws + OFF_TABR1);
  int* tns        = (int*)(ws + OFF_TNS);
  int* lists      = (int*)(ws + OFF_LISTS);
  float* wlists   = (float*)(ws + OFF_WLISTS);
  unsigned short* hbuf = (unsigned short*)(ws + OFF_HBUF);

  hipMemsetAsync(counts, 0, 64 * sizeof(int), stream);
  gate_logits_kernel<<<dim3(NTOK / 16), 256, 0, stream>>>(x, gw, gb, logits, (unsigned short*)0);
  topk_kernel<<<dim3(NTOK / 256), 256, 0, stream>>>(logits, counts, lists, wlists);
  scan_kernel<<<1, 1, 0, stream>>>(counts, seg_count, seg_hbase, tableA, tableR0, tableR1, tns);
  ffn1_kernel<<<dim3(384, 6), 256, 0, stream>>>(x, sw1, sb1, rw1, rb1, lists,
                                                seg_count, seg_hbase, tableA, tns, hbuf);
  ffn2_shared_kernel<<<dim3(64, 80), 256, 0, stream>>>(hbuf, sw2, sb2, out);
  ffn2_routed_kernel<<<dim3(128, 80), 256, 0, stream>>>(hbuf, rw2, rb2, lists, wlists,
                                                        counts, seg_hbase, tableR0, tns, 1, out);
  ffn2_routed_kernel<<<dim3(128, 80), 256, 0, stream>>>(hbuf, rw2, rb2, lists, wlists,
                                                        counts, seg_hbase, tableR1, tns, 2, out);
}

// Round 8
// 624.024 us; speedup vs baseline: 1.1046x; 1.0353x over previous
//
#include <hip/hip_runtime.h>
#include <math.h>

// ---------------- problem constants ----------------
#define NTOK 4096      // B*T
#define DM   5120      // d_model
#define FD   384       // ffn_dim
#define NE   32        // routed experts

typedef float  f32x4  __attribute__((ext_vector_type(4)));
typedef __bf16 bf16x8 __attribute__((ext_vector_type(8)));
typedef unsigned short us2 __attribute__((ext_vector_type(2)));
typedef unsigned short us4 __attribute__((ext_vector_type(4)));
typedef unsigned short us8 __attribute__((ext_vector_type(8)));

__device__ __forceinline__ unsigned short f2bf(float f) {
  unsigned int u = __float_as_uint(f);
  u += 0x7fffu + ((u >> 16) & 1u);     // RNE
  return (unsigned short)(u >> 16);
}

__device__ __forceinline__ float gelu_f(float v) {
  return 0.5f * v * (1.0f + erff(v * 0.70710678118654752f));  // exact erf gelu
}

__device__ __forceinline__ f32x4 mfma16(bf16x8 a, bf16x8 b, f32x4 c) {
  return __builtin_amdgcn_mfma_f32_16x16x32_bf16(a, b, c, 0, 0, 0);
}

// XOR-swizzled LDS tile read (tile row stride = 64 bf16 = 128B; g = 16B group)
__device__ __forceinline__ bf16x8 fragld(const unsigned short* t, int row, int g) {
  return *(const bf16x8*)(t + row * 64 + ((g ^ (row & 7)) << 3));
}

// async global->LDS, 16B/lane. LDS dest = wave-uniform base + lane*16 (linear).
// Swizzle achieved by pre-swizzling the per-lane GLOBAL source (rule 21).
__device__ __forceinline__ void gld16(const void* g, void* l) {
  __builtin_amdgcn_global_load_lds(
      (const __attribute__((address_space(1))) unsigned int*)g,
      (__attribute__((address_space(3))) unsigned int*)l, 16, 0, 0);
}

// ================= OLD-PATH ws layout (fallback; 15.3 MB) =================
#define OFF_LOGITS 0
#define OFF_COUNTS 524288
#define OFF_SEGC   524800
#define OFF_SEGB   525312
#define OFF_TABA   525824
#define OFF_TABR0  528896
#define OFF_TABR1  529920
#define OFF_TNS    530944
#define OFF_LISTS  531456
#define OFF_WLISTS 1580032
#define OFF_HBUF   2628608
#define WS_OLD     15260672UL

// ================= NEW-PATH ws layout =================
#define L_LOGITS 0UL
#define L_COUNTS 524288UL
#define L_HBASE  524544UL
#define L_TABA   524800UL
#define L_TABR0  527360UL
#define L_TABR1  528384UL
#define L_TNS    529408UL
#define L_LISTS  529536UL
#define L_WLIST  1578112UL
#define L_HBUF   2626688UL
#define L_XBF    15258752UL
#define L_W1T    57201792UL
#define L_W2ST   190895232UL
#define L_W2RT   198759552UL
#define WS_NEW   324588672UL

// ---------------- gate v3: fp64-accurate logits + x->bf16 fold ----------------
__global__ __launch_bounds__(256) void gate_v3(
    const float* __restrict__ x, const float* __restrict__ gw,
    const float* __restrict__ gb, float* __restrict__ logits,
    unsigned short* __restrict__ xbf)
{
  __shared__ __align__(16) char gsm[22656];
  float*  xs = (float*)gsm;              // [8][132] f32
  float*  gs = (float*)(gsm + 4224);     // [128][36] f32
  double* ps = (double*)(gsm + 4224);    // [8][8][32] f64, reused after K loop

  int tid = threadIdx.x;
  int t0 = blockIdx.x * 8;

  int col  = tid & 15;
  int row  = (tid >> 4) & 1;
  int part = tid >> 5;
  int e0 = col * 2;

  double a[4][2];
  #pragma unroll
  for (int i = 0; i < 4; ++i) { a[i][0] = 0.0; a[i][1] = 0.0; }

  int sx_r = tid >> 5;
  int sx_c = (tid & 31) * 4;
  const float* xg = x + (size_t)(t0 + sx_r) * DM + sx_c;
  unsigned short* xo = xbf + (size_t)(t0 + sx_r) * DM + sx_c;

  for (int k0 = 0; k0 < DM; k0 += 128) {
    float4 xv4 = *(const float4*)(xg + k0);
    *(float4*)&xs[sx_r * 132 + sx_c] = xv4;
    us4 hx = {f2bf(xv4.x), f2bf(xv4.y), f2bf(xv4.z), f2bf(xv4.w)};
    *(us4*)(xo + k0) = hx;
    #pragma unroll
    for (int p = 0; p < 4; ++p) {
      int idx = p * 256 + tid;
      int r = idx >> 3, q = (idx & 7) * 4;
      float4 g4 = *(const float4*)(gw + (size_t)(k0 + r) * NE + q);
      *(float4*)&gs[r * 36 + q] = g4;
    }
    __syncthreads();
    #pragma unroll
    for (int kk = 0; kk < 16; ++kk) {
      int k = part * 16 + kk;
      double g0 = (double)gs[k * 36 + e0];
      double g1 = (double)gs[k * 36 + e0 + 1];
      #pragma unroll
      for (int i = 0; i < 4; ++i) {
        double xv = (double)xs[(row * 4 + i) * 132 + k];
        a[i][0] = fma(xv, g0, a[i][0]);
        a[i][1] = fma(xv, g1, a[i][1]);
      }
    }
    __syncthreads();
  }

  #pragma unroll
  for (int i = 0; i < 4; ++i) {
    double2 v; v.x = a[i][0]; v.y = a[i][1];
    *(double2*)&ps[(size_t)part * 256 + (row * 4 + i) * 32 + e0] = v;
  }
  __syncthreads();
  {
    int t = tid >> 5, e = tid & 31;
    double s = 0.0;
    #pragma unroll
    for (int p = 0; p < 8; ++p) s += ps[(size_t)p * 256 + t * 32 + e];
    logits[(size_t)(t0 + t) * NE + e] = (float)s + gb[e];
  }
}

// ---------------- old gate (fallback path only) ----------------
__global__ __launch_bounds__(256) void gate_logits_kernel(
    const float* __restrict__ x, const float* __restrict__ gw,
    const float* __restrict__ gb, float* __restrict__ logits,
    unsigned short* __restrict__ xbf)
{
  __shared__ float xs[16][33];
  __shared__ float gs[32][33];
  int tid = threadIdx.x;
  int t0 = blockIdx.x * 16;
  int r = tid >> 4;
  int e0 = (tid & 15) * 2;
  double a0 = 0.0, a1 = 0.0;
  for (int k0 = 0; k0 < DM; k0 += 32) {
    {
      int rr = tid >> 4, cc = (tid & 15) * 2;
      const float* s = x + (size_t)(t0 + rr) * DM + k0 + cc;
      float s0 = s[0], s1 = s[1];
      xs[rr][cc] = s0; xs[rr][cc + 1] = s1;
      if (xbf) {
        us2 h = {f2bf(s0), f2bf(s1)};
        *(us2*)(xbf + (size_t)(t0 + rr) * DM + k0 + cc) = h;
      }
    }
    {
      int rr = tid >> 3, cc = (tid & 7) * 4;
      float4 v = *(const float4*)(gw + (size_t)(k0 + rr) * NE + cc);
      gs[rr][cc] = v.x; gs[rr][cc + 1] = v.y; gs[rr][cc + 2] = v.z; gs[rr][cc + 3] = v.w;
    }
    __syncthreads();
    #pragma unroll
    for (int kk = 0; kk < 32; ++kk) {
      double a = (double)xs[r][kk];
      a0 += a * (double)gs[kk][e0];
      a1 += a * (double)gs[kk][e0 + 1];
    }
    __syncthreads();
  }
  logits[(size_t)(t0 + r) * NE + e0]     = (float)a0 + gb[e0];
  logits[(size_t)(t0 + r) * NE + e0 + 1] = (float)a1 + gb[e0 + 1];
}

// ---------------- softmax + top2 + scatter ----------------
__global__ void topk_kernel(const float* __restrict__ logits, int* __restrict__ counts,
                            int* __restrict__ lists, float* __restrict__ wlists)
{
  int t = blockIdx.x * blockDim.x + threadIdx.x;
  if (t >= NTOK) return;
  float l[32];
  const float4* lp = (const float4*)(logits + (size_t)t * NE);
  #pragma unroll
  for (int i = 0; i < 8; ++i) {
    float4 v = lp[i];
    l[i*4] = v.x; l[i*4+1] = v.y; l[i*4+2] = v.z; l[i*4+3] = v.w;
  }
  float mx = l[0];
  #pragma unroll
  for (int e = 1; e < 32; ++e) mx = fmaxf(mx, l[e]);
  float s = 0.f;
  #pragma unroll
  for (int e = 0; e < 32; ++e) s += expf(l[e] - mx);
  int i1 = 0; float b1 = l[0];
  #pragma unroll
  for (int e = 1; e < 32; ++e) if (l[e] > b1) { b1 = l[e]; i1 = e; }
  int i2 = -1; float b2 = -3.4e38f;
  #pragma unroll
  for (int e = 0; e < 32; ++e) if (e != i1 && l[e] > b2) { b2 = l[e]; i2 = e; }
  float p1 = expf(b1 - mx) / s;
  float p2 = expf(b2 - mx) / s;
  int pos = atomicAdd(&counts[i1], 1);
  lists [(size_t)i1 * NTOK + pos] = t;
  wlists[(size_t)i1 * NTOK + pos] = p1;
  pos = atomicAdd(&counts[32 + i2], 1);
  lists [(size_t)(32 + i2) * NTOK + pos] = t;
  wlists[(size_t)(32 + i2) * NTOK + pos] = p2;
}

// ================================================================
// ======================= OLD PATH (fallback) =====================
// ================================================================
__global__ void scan_kernel(const int* __restrict__ counts, int* __restrict__ seg_count,
                            int* __restrict__ seg_hbase, int2* __restrict__ tableA,
                            int2* __restrict__ tableR0, int2* __restrict__ tableR1,
                            int* __restrict__ tns)
{
  if (threadIdx.x != 0 || blockIdx.x != 0) return;
  seg_count[0] = NTOK; seg_hbase[0] = 0;
  seg_count[1] = NTOK; seg_hbase[1] = NTOK;
  int base = 2 * NTOK;
  for (int li = 0; li < 64; ++li) {
    int c = counts[li];
    seg_count[2 + li] = c; seg_hbase[2 + li] = base; base += c;
  }
  int nA = 0;
  for (int s = 0; s < 66; ++s) {
    int c = seg_count[s];
    for (int m0 = 0; m0 < c; m0 += 64) { tableA[nA].x = s; tableA[nA].y = m0; ++nA; }
  }
  int nR0 = 0;
  for (int li = 0; li < 32; ++li)
    for (int m0 = 0; m0 < counts[li]; m0 += 64) { tableR0[nR0].x = li; tableR0[nR0].y = m0; ++nR0; }
  int nR1 = 0;
  for (int li = 32; li < 64; ++li)
    for (int m0 = 0; m0 < counts[li]; m0 += 64) { tableR1[nR1].x = li; tableR1[nR1].y = m0; ++nR1; }
  tns[0] = nA; tns[1] = nR0; tns[2] = nR1;
}

__global__ __launch_bounds__(256) void ffn1_kernel(
    const float* __restrict__ x,
    const float* __restrict__ sw1, const float* __restrict__ sb1,
    const float* __restrict__ rw1, const float* __restrict__ rb1,
    const int* __restrict__ lists,
    const int* __restrict__ seg_count, const int* __restrict__ seg_hbase,
    const int2* __restrict__ tableA, const int* __restrict__ tns,
    unsigned short* __restrict__ hbuf)
{
  if ((int)blockIdx.x >= tns[0]) return;
  int2 ent = tableA[blockIdx.x];
  int seg = ent.x, m0 = ent.y;
  int cnt = seg_count[seg];
  int hbase = seg_hbase[seg];
  int n0 = blockIdx.y * 64;
  const float *w1, *b1;
  if (seg < 2) { w1 = sw1 + (size_t)seg * DM * FD; b1 = sb1 + (size_t)seg * FD; }
  else { int e = (seg - 2) & 31; w1 = rw1 + (size_t)e * DM * FD; b1 = rb1 + (size_t)e * FD; }
  __shared__ int toks[64];
  __shared__ unsigned short As[64][44];
  __shared__ unsigned short Bs[64][44];
  int tid = threadIdx.x;
  if (tid < 64) {
    int i = m0 + tid;
    int tk = 0;
    if (i < cnt) tk = (seg < 2) ? i : lists[(size_t)(seg - 2) * NTOK + i];
    toks[tid] = tk;
  }
  __syncthreads();
  int lane = tid & 63, wave = tid >> 6;
  int wr = (wave >> 1) * 32, wc = (wave & 1) * 32;
  int l15 = lane & 15, kb = (lane >> 4) * 8;
  f32x4 zz = {0.f, 0.f, 0.f, 0.f};
  f32x4 acc[2][2];
  #pragma unroll
  for (int i = 0; i < 2; ++i)
    #pragma unroll
    for (int j = 0; j < 2; ++j) acc[i][j] = zz;
  int ar = tid >> 2, ac = (tid & 3) * 8;
  const float* axp = x + (size_t)toks[ar] * DM + ac;
  int br = tid >> 3, bc = (tid & 7) * 8;
  const float* bwp = w1 + (size_t)br * FD + n0 + bc;
  for (int k0 = 0; k0 < DM; k0 += 32) {
    float4 a0 = *(const float4*)(axp + k0);
    float4 a1 = *(const float4*)(axp + k0 + 4);
    float4 w0 = *(const float4*)bwp;
    float4 w4 = *(const float4*)(bwp + 4);
    bwp += (size_t)32 * FD;
    us4 pa0 = {f2bf(a0.x), f2bf(a0.y), f2bf(a0.z), f2bf(a0.w)};
    us4 pa1 = {f2bf(a1.x), f2bf(a1.y), f2bf(a1.z), f2bf(a1.w)};
    *(us4*)&As[ar][ac] = pa0;
    *(us4*)&As[ar][ac + 4] = pa1;
    Bs[bc + 0][br] = f2bf(w0.x); Bs[bc + 1][br] = f2bf(w0.y);
    Bs[bc + 2][br] = f2bf(w0.z); Bs[bc + 3][br] = f2bf(w0.w);
    Bs[bc + 4][br] = f2bf(w4.x); Bs[bc + 5][br] = f2bf(w4.y);
    Bs[bc + 6][br] = f2bf(w4.z); Bs[bc + 7][br] = f2bf(w4.w);
    __syncthreads();
    bf16x8 af0, af1, bf0, bf1;
    {
      const unsigned short* p = &As[wr + l15][kb];
      af0 = *(const bf16x8*)p;
      af1 = *(const bf16x8*)(&As[wr + 16 + l15][kb]);
      bf0 = *(const bf16x8*)(&Bs[wc + l15][kb]);
      bf1 = *(const bf16x8*)(&Bs[wc + 16 + l15][kb]);
    }
    acc[0][0] = mfma16(af0, bf0, acc[0][0]);
    acc[0][1] = mfma16(af0, bf1, acc[0][1]);
    acc[1][0] = mfma16(af1, bf0, acc[1][0]);
    acc[1][1] = mfma16(af1, bf1, acc[1][1]);
    __syncthreads();
  }
  int rb4 = (lane >> 4) * 4;
  #pragma unroll
  for (int mi = 0; mi < 2; ++mi) {
    #pragma unroll
    for (int rg = 0; rg < 4; ++rg) {
      int gi = m0 + wr + mi * 16 + rb4 + rg;
      if (gi < cnt) {
        #pragma unroll
        for (int ni = 0; ni < 2; ++ni) {
          int ncol = n0 + wc + ni * 16 + l15;
          float v = acc[mi][ni][rg] + b1[ncol];
          hbuf[(size_t)(hbase + gi) * FD + ncol] = f2bf(gelu_f(v));
        }
      }
    }
  }
}

__global__ __launch_bounds__(256) void ffn2_shared_kernel(
    const unsigned short* __restrict__ hbuf,
    const float* __restrict__ sw2, const float* __restrict__ sb2,
    float* __restrict__ out)
{
  int m0 = blockIdx.x * 64;
  int n0 = blockIdx.y * 64;
  __shared__ unsigned short As[64][44];
  __shared__ unsigned short Bs[64][44];
  int tid = threadIdx.x;
  int lane = tid & 63, wave = tid >> 6;
  int wr = (wave >> 1) * 32, wc = (wave & 1) * 32;
  int l15 = lane & 15, kb = (lane >> 4) * 8;
  f32x4 zz = {0.f, 0.f, 0.f, 0.f};
  f32x4 acc[2][2];
  #pragma unroll
  for (int i = 0; i < 2; ++i)
    #pragma unroll
    for (int j = 0; j < 2; ++j) acc[i][j] = zz;
  int ar = tid >> 2, ac = (tid & 3) * 8;
  int br = tid >> 3, bc = (tid & 7) * 8;
  const float* bwp = sw2 + (size_t)br * DM + n0 + bc;
  for (int k0 = 0; k0 < 2 * FD; k0 += 32) {
    int side = (k0 >= FD) ? 1 : 0;
    const unsigned short* ap =
        hbuf + (size_t)(side * NTOK + m0 + ar) * FD + (k0 - side * FD) + ac;
    us8 av = *(const us8*)ap;
    float4 w0 = *(const float4*)bwp;
    float4 w4 = *(const float4*)(bwp + 4);
    bwp += (size_t)32 * DM;
    us4 alo = {av[0], av[1], av[2], av[3]};
    us4 ahi = {av[4], av[5], av[6], av[7]};
    *(us4*)&As[ar][ac] = alo;
    *(us4*)&As[ar][ac + 4] = ahi;
    Bs[bc + 0][br] = f2bf(w0.x); Bs[bc + 1][br] = f2bf(w0.y);
    Bs[bc + 2][br] = f2bf(w0.z); Bs[bc + 3][br] = f2bf(w0.w);
    Bs[bc + 4][br] = f2bf(w4.x); Bs[bc + 5][br] = f2bf(w4.y);
    Bs[bc + 6][br] = f2bf(w4.z); Bs[bc + 7][br] = f2bf(w4.w);
    __syncthreads();
    bf16x8 af0 = *(const bf16x8*)(&As[wr + l15][kb]);
    bf16x8 af1 = *(const bf16x8*)(&As[wr + 16 + l15][kb]);
    bf16x8 bf0 = *(const bf16x8*)(&Bs[wc + l15][kb]);
    bf16x8 bf1 = *(const bf16x8*)(&Bs[wc + 16 + l15][kb]);
    acc[0][0] = mfma16(af0, bf0, acc[0][0]);
    acc[0][1] = mfma16(af0, bf1, acc[0][1]);
    acc[1][0] = mfma16(af1, bf0, acc[1][0]);
    acc[1][1] = mfma16(af1, bf1, acc[1][1]);
    __syncthreads();
  }
  int rb4 = (lane >> 4) * 4;
  #pragma unroll
  for (int mi = 0; mi < 2; ++mi) {
    #pragma unroll
    for (int rg = 0; rg < 4; ++rg) {
      int row = m0 + wr + mi * 16 + rb4 + rg;
      #pragma unroll
      for (int ni = 0; ni < 2; ++ni) {
        int ncol = n0 + wc + ni * 16 + l15;
        out[(size_t)row * DM + ncol] = acc[mi][ni][rg] + sb2[ncol] + sb2[DM + ncol];
      }
    }
  }
}

__global__ __launch_bounds__(256) void ffn2_routed_kernel(
    const unsigned short* __restrict__ hbuf,
    const float* __restrict__ rw2, const float* __restrict__ rb2,
    const int* __restrict__ lists, const float* __restrict__ wlists,
    const int* __restrict__ counts, const int* __restrict__ seg_hbase,
    const int2* __restrict__ tableR, const int* __restrict__ tns, int tidx,
    float* __restrict__ out)
{
  if ((int)blockIdx.x >= tns[tidx]) return;
  int2 ent = tableR[blockIdx.x];
  int li = ent.x, m0 = ent.y;
  int cnt = counts[li];
  int hbase = seg_hbase[2 + li];
  int e = li & 31;
  int n0 = blockIdx.y * 64;
  const float* w2 = rw2 + (size_t)e * FD * DM;
  const float* b2 = rb2 + (size_t)e * DM;
  __shared__ unsigned short As[64][44];
  __shared__ unsigned short Bs[64][44];
  int tid = threadIdx.x;
  int lane = tid & 63, wave = tid >> 6;
  int wr = (wave >> 1) * 32, wc = (wave & 1) * 32;
  int l15 = lane & 15, kb = (lane >> 4) * 8;
  f32x4 zz = {0.f, 0.f, 0.f, 0.f};
  f32x4 acc[2][2];
  #pragma unroll
  for (int i = 0; i < 2; ++i)
    #pragma unroll
    for (int j = 0; j < 2; ++j) acc[i][j] = zz;
  int ar = tid >> 2, ac = (tid & 3) * 8;
  const unsigned short* ap = hbuf + (size_t)(hbase + m0 + ar) * FD + ac;
  int br = tid >> 3, bc = (tid & 7) * 8;
  const float* bwp = w2 + (size_t)br * DM + n0 + bc;
  for (int k0 = 0; k0 < FD; k0 += 32) {
    us8 av = *(const us8*)(ap + k0);
    float4 w0 = *(const float4*)bwp;
    float4 w4 = *(const float4*)(bwp + 4);
    bwp += (size_t)32 * DM;
    us4 alo = {av[0], av[1], av[2], av[3]};
    us4 ahi = {av[4], av[5], av[6], av[7]};
    *(us4*)&As[ar][ac] = alo;
    *(us4*)&As[ar][ac + 4] = ahi;
    Bs[bc + 0][br] = f2bf(w0.x); Bs[bc + 1][br] = f2bf(w0.y);
    Bs[bc + 2][br] = f2bf(w0.z); Bs[bc + 3][br] = f2bf(w0.w);
    Bs[bc + 4][br] = f2bf(w4.x); Bs[bc + 5][br] = f2bf(w4.y);
    Bs[bc + 6][br] = f2bf(w4.z); Bs[bc + 7][br] = f2bf(w4.w);
    __syncthreads();
    bf16x8 af0 = *(const bf16x8*)(&As[wr + l15][kb]);
    bf16x8 af1 = *(const bf16x8*)(&As[wr + 16 + l15][kb]);
    bf16x8 bf0 = *(const bf16x8*)(&Bs[wc + l15][kb]);
    bf16x8 bf1 = *(const bf16x8*)(&Bs[wc + 16 + l15][kb]);
    acc[0][0] = mfma16(af0, bf0, acc[0][0]);
    acc[0][1] = mfma16(af0, bf1, acc[0][1]);
    acc[1][0] = mfma16(af1, bf0, acc[1][0]);
    acc[1][1] = mfma16(af1, bf1, acc[1][1]);
    __syncthreads();
  }
  int rb4 = (lane >> 4) * 4;
  #pragma unroll
  for (int mi = 0; mi < 2; ++mi) {
    #pragma unroll
    for (int rg = 0; rg < 4; ++rg) {
      int gi = m0 + wr + mi * 16 + rb4 + rg;
      if (gi < cnt) {
        int tok = lists[(size_t)li * NTOK + gi];
        float wgt = wlists[(size_t)li * NTOK + gi];
        #pragma unroll
        for (int ni = 0; ni < 2; ++ni) {
          int ncol = n0 + wc + ni * 16 + l15;
          float v = (acc[mi][ni][rg] + b2[ncol]) * wgt;
          out[(size_t)tok * DM + ncol] += v;
        }
      }
    }
  }
}

// ================================================================
// ========================= NEW PATH =============================
// ================================================================

// table builder: tableA now 128-row tiles (all segs); tableR stays 64-row
__global__ void scan_v4(const int* __restrict__ counts, int* __restrict__ hbase_g,
                        int2* __restrict__ tableA, int2* __restrict__ tableR0,
                        int2* __restrict__ tableR1, int* __restrict__ tns)
{
  __shared__ int cnt[64], tprefA[64], tpref0[32], tpref1[32], hpref[64];
  int t = threadIdx.x;
  if (t < 64) cnt[t] = counts[t];
  __syncthreads();
  if (t == 0) {
    int hb = 2 * NTOK, ta = 64, t0 = 0, t1 = 0;  // 64 shared 128-row tiles first
    for (int i = 0; i < 64; ++i) {
      int ntA = (cnt[i] + 127) >> 7;
      int nt = (cnt[i] + 63) >> 6;
      hpref[i] = hb; hb += cnt[i];
      tprefA[i] = ta; ta += ntA;
      if (i < 32) { tpref0[i] = t0; t0 += nt; }
      else        { tpref1[i - 32] = t1; t1 += nt; }
    }
    tns[0] = ta; tns[1] = t0; tns[2] = t1;
  }
  __syncthreads();
  if (t < 64) {   // shared tiles: seg = t>>5, m0 = (t&31)*128
    int2 ent; ent.x = t >> 5; ent.y = (t & 31) * 128;
    tableA[t] = ent;
  }
  if (t < 64) {
    hbase_g[t] = hpref[t];
    int ntA = (cnt[t] + 127) >> 7;
    for (int j = 0; j < ntA; ++j) {
      int2 ent; ent.x = 2 + t; ent.y = j * 128;
      tableA[tprefA[t] + j] = ent;
    }
    int nt = (cnt[t] + 63) >> 6;
    for (int j = 0; j < nt; ++j) {
      int2 entR; entR.x = t; entR.y = j * 64;
      if (t < 32) tableR0[tpref0[t] + j] = entR;
      else        tableR1[tpref1[t - 32] + j] = entR;
    }
  }
}

// transpose-convert w1 f32 [seg][k][n] -> bf16 [seg][n][k]
// LDS swizzle: element (row,c) at col c ^ (((row>>4)&3)<<4); float4 alignment kept.
__global__ __launch_bounds__(256) void conv_w1_v2(
    const float* __restrict__ sw1, const float* __restrict__ rw1,
    unsigned short* __restrict__ w1T)
{
  int seg = blockIdx.x;
  int k0 = blockIdx.y * 64;
  int n0 = blockIdx.z * 64;
  const float* src = (seg < 2) ? sw1 + (size_t)seg * DM * FD
                               : rw1 + (size_t)(seg - 2) * DM * FD;
  __shared__ float ls[64][68];
  int tid = threadIdx.x;
  int r = tid >> 4, c4 = (tid & 15) * 4;
  #pragma unroll
  for (int p = 0; p < 4; ++p) {
    int row = r + p * 16;
    float4 v = *(const float4*)(src + (size_t)(k0 + row) * FD + n0 + c4);
    *(float4*)&ls[row][c4 ^ (((row >> 4) & 3) << 4)] = v;
  }
  __syncthreads();
  int n = tid >> 2, kseg = (tid & 3) * 16;
  int swz = ((kseg >> 4) & 3) << 4;
  unsigned short tmp[16];
  #pragma unroll
  for (int j = 0; j < 16; ++j) tmp[j] = f2bf(ls[kseg + j][n ^ swz]);
  unsigned short* dst = w1T + (size_t)seg * FD * DM + (size_t)(n0 + n) * DM + k0 + kseg;
  us8 o0 = {tmp[0], tmp[1], tmp[2], tmp[3], tmp[4], tmp[5], tmp[6], tmp[7]};
  us8 o1 = {tmp[8], tmp[9], tmp[10], tmp[11], tmp[12], tmp[13], tmp[14], tmp[15]};
  *(us8*)dst = o0;
  *(us8*)(dst + 8) = o1;
}

// transpose-convert w2 (same swizzle)
__global__ __launch_bounds__(256) void conv_w2_v2(
    const float* __restrict__ sw2, const float* __restrict__ rw2,
    unsigned short* __restrict__ w2sT, unsigned short* __restrict__ w2rT)
{
  int e = blockIdx.x;
  int K = (e == 0) ? 2 * FD : FD;
  int k0 = blockIdx.y * 64;
  if (k0 >= K) return;
  int n0 = blockIdx.z * 64;
  const float* src = (e == 0) ? sw2 : rw2 + (size_t)(e - 1) * FD * DM;
  unsigned short* dstb = (e == 0) ? w2sT : w2rT + (size_t)(e - 1) * DM * FD;
  __shared__ float ls[64][68];
  int tid = threadIdx.x;
  int r = tid >> 4, c4 = (tid & 15) * 4;
  #pragma unroll
  for (int p = 0; p < 4; ++p) {
    int row = r + p * 16;
    float4 v = *(const float4*)(src + (size_t)(k0 + row) * DM + n0 + c4);
    *(float4*)&ls[row][c4 ^ (((row >> 4) & 3) << 4)] = v;
  }
  __syncthreads();
  int n = tid >> 2, kseg = (tid & 3) * 16;
  int swz = ((kseg >> 4) & 3) << 4;
  unsigned short tmp[16];
  #pragma unroll
  for (int j = 0; j < 16; ++j) tmp[j] = f2bf(ls[kseg + j][n ^ swz]);
  unsigned short* dst = dstb + (size_t)(n0 + n) * K + k0 + kseg;
  us8 o0 = {tmp[0], tmp[1], tmp[2], tmp[3], tmp[4], tmp[5], tmp[6], tmp[7]};
  us8 o1 = {tmp[8], tmp[9], tmp[10], tmp[11], tmp[12], tmp[13], tmp[14], tmp[15]};
  *(us8*)dst = o0;
  *(us8*)(dst + 8) = o1;
}

// unified ffn1 v4: 128x128 tiles (m97 geometry), K=5120, global_load_lds staging.
// 4 waves x (64x64 out, acc 4x4): 32 MFMA : 16 ds_read : 8 gld16 per wave-K-step.
__global__ __launch_bounds__(256) void ffn1_v4(
    const unsigned short* __restrict__ xbf, const unsigned short* __restrict__ w1T,
    const float* __restrict__ sb1, const float* __restrict__ rb1,
    const int* __restrict__ lists, const int* __restrict__ counts,
    const int* __restrict__ hbase_g, const int2* __restrict__ tableA,
    const int* __restrict__ tns, unsigned short* __restrict__ hbuf)
{
  if ((int)blockIdx.x >= tns[0]) return;
  int2 ent = tableA[blockIdx.x];
  int seg = ent.x, m0 = ent.y;
  int cnt, hbase, wseg;
  const float* b1;
  if (seg < 2) {
    cnt = NTOK; hbase = seg * NTOK; b1 = sb1 + seg * FD; wseg = seg;
  } else {
    int li = seg - 2;
    int e = li & 31;
    cnt = counts[li]; hbase = hbase_g[li];
    b1 = rb1 + (size_t)e * FD;
    wseg = 2 + e;
  }
  int n0 = blockIdx.y * 128;
  const unsigned short* w1 = w1T + (size_t)wseg * FD * DM;

  __shared__ int toks[128];
  __shared__ __align__(16) unsigned short As[128 * 64];
  __shared__ __align__(16) unsigned short Bs[128 * 64];

  int tid = threadIdx.x;
  if (tid < 128) {
    int i = m0 + tid;
    int tk;
    if (seg < 2) tk = (i < cnt) ? i : 0;
    else tk = (i < cnt) ? lists[(size_t)(seg - 2) * NTOK + i] : 0;
    toks[tid] = tk;
  }
  __syncthreads();

  int lane = tid & 63, wave = tid >> 6;
  int wr = (wave >> 1) * 64, wc = (wave & 1) * 64;
  int l15 = lane & 15, l4 = lane >> 4;

  f32x4 zz = {0.f, 0.f, 0.f, 0.f};
  f32x4 acc[4][4];
  #pragma unroll
  for (int i = 0; i < 4; ++i)
    #pragma unroll
    for (int j = 0; j < 4; ++j) acc[i][j] = zz;

  // staging: chunk = 8 rows (1KB); 4 A-chunks + 4 B-chunks per wave
  int g = lane & 7, lr = lane >> 3;
  const unsigned short* agsrc[4];  unsigned short* aldst[4];
  const unsigned short* bgsrc[4];  unsigned short* bldst[4];
  #pragma unroll
  for (int p = 0; p < 4; ++p) {
    int row = wave * 32 + p * 8 + lr;
    int sw = (g ^ (row & 7)) << 3;
    agsrc[p] = xbf + (size_t)toks[row] * DM + sw;
    aldst[p] = As + (wave * 32 + p * 8) * 64;   // wave-uniform
    bgsrc[p] = w1 + (size_t)(n0 + row) * DM + sw;
    bldst[p] = Bs + (wave * 32 + p * 8) * 64;
  }

  for (int k0 = 0; k0 < DM; k0 += 64) {
    #pragma unroll
    for (int p = 0; p < 4; ++p) gld16(agsrc[p] + k0, aldst[p]);
    #pragma unroll
    for (int p = 0; p < 4; ++p) gld16(bgsrc[p] + k0, bldst[p]);
    __syncthreads();
    #pragma unroll
    for (int kk = 0; kk < 2; ++kk) {
      bf16x8 af[4], bfr[4];
      #pragma unroll
      for (int mi = 0; mi < 4; ++mi) af[mi] = fragld(As, wr + mi * 16 + l15, kk * 4 + l4);
      #pragma unroll
      for (int ni = 0; ni < 4; ++ni) bfr[ni] = fragld(Bs, wc + ni * 16 + l15, kk * 4 + l4);
      #pragma unroll
      for (int mi = 0; mi < 4; ++mi)
        #pragma unroll
        for (int ni = 0; ni < 4; ++ni) acc[mi][ni] = mfma16(af[mi], bfr[ni], acc[mi][ni]);
    }
    __syncthreads();
  }

  int rb4 = l4 * 4;
  #pragma unroll
  for (int mi = 0; mi < 4; ++mi) {
    #pragma unroll
    for (int rg = 0; rg < 4; ++rg) {
      int gi = m0 + wr + mi * 16 + rb4 + rg;
      if (gi < cnt) {
        #pragma unroll
        for (int ni = 0; ni < 4; ++ni) {
          int ncol = n0 + wc + ni * 16 + l15;
          float v = acc[mi][ni][rg] + b1[ncol];
          hbuf[(size_t)(hbase + gi) * FD + ncol] = f2bf(gelu_f(v));
        }
      }
    }
  }
}

// ffn2 shared: dense 128x128, K=768, global_load_lds staging
__global__ __launch_bounds__(256) void ffn2_shared_v2(
    const unsigned short* __restrict__ hbuf, const unsigned short* __restrict__ w2sT,
    const float* __restrict__ sb2, float* __restrict__ out)
{
  int m0 = blockIdx.x * 128;
  int n0 = blockIdx.y * 128;

  __shared__ __align__(16) unsigned short As[128 * 64];
  __shared__ __align__(16) unsigned short Bs[128 * 64];

  int tid = threadIdx.x;
  int lane = tid & 63, wave = tid >> 6;
  int wr = (wave >> 1) * 64, wc = (wave & 1) * 64;
  int l15 = lane & 15, l4 = lane >> 4;

  f32x4 zz = {0.f, 0.f, 0.f, 0.f};
  f32x4 acc[4][4];
  #pragma unroll
  for (int i = 0; i < 4; ++i)
    #pragma unroll
    for (int j = 0; j < 4; ++j) acc[i][j] = zz;

  int g = lane & 7, lr = lane >> 3;
  int prow[4];  unsigned short* aldst[4];  unsigned short* bldst[4];
  const unsigned short* bgsrc[4];
  int aswz[4];
  #pragma unroll
  for (int p = 0; p < 4; ++p) {
    prow[p] = wave * 32 + p * 8 + lr;
    aldst[p] = As + (wave * 32 + p * 8) * 64;
    bldst[p] = Bs + (wave * 32 + p * 8) * 64;
    aswz[p] = (g ^ (prow[p] & 7)) << 3;
    bgsrc[p] = w2sT + (size_t)(n0 + prow[p]) * (2 * FD) + aswz[p];
  }

  for (int k0 = 0; k0 < 2 * FD; k0 += 64) {
    int side = (k0 >= FD) ? 1 : 0;
    int kk0 = k0 - side * FD;
    #pragma unroll
    for (int p = 0; p < 4; ++p)
      gld16(hbuf + (size_t)(side * NTOK + m0 + prow[p]) * FD + kk0 + aswz[p], aldst[p]);
    #pragma unroll
    for (int p = 0; p < 4; ++p) gld16(bgsrc[p] + k0, bldst[p]);
    __syncthreads();
    #pragma unroll
    for (int kk = 0; kk < 2; ++kk) {
      bf16x8 af[4], bfr[4];
      #pragma unroll
      for (int mi = 0; mi < 4; ++mi) af[mi] = fragld(As, wr + mi * 16 + l15, kk * 4 + l4);
      #pragma unroll
      for (int ni = 0; ni < 4; ++ni) bfr[ni] = fragld(Bs, wc + ni * 16 + l15, kk * 4 + l4);
      #pragma unroll
      for (int mi = 0; mi < 4; ++mi)
        #pragma unroll
        for (int ni = 0; ni < 4; ++ni) acc[mi][ni] = mfma16(af[mi], bfr[ni], acc[mi][ni]);
    }
    __syncthreads();
  }

  int rb4 = l4 * 4;
  #pragma unroll
  for (int mi = 0; mi < 4; ++mi) {
    #pragma unroll
    for (int rg = 0; rg < 4; ++rg) {
      int row = m0 + wr + mi * 16 + rb4 + rg;
      #pragma unroll
      for (int ni = 0; ni < 4; ++ni) {
        int ncol = n0 + wc + ni * 16 + l15;
        out[(size_t)row * DM + ncol] = acc[mi][ni][rg] + sb2[ncol] + sb2[DM + ncol];
      }
    }
  }
}

// ffn2 routed: 64x128, K=384, global_load_lds staging, out += w*(h@w2+b2)
__global__ __launch_bounds__(256) void ffn2_routed_v2(
    const unsigned short* __restrict__ hbuf, const unsigned short* __restrict__ w2rT,
    const float* __restrict__ rb2, const int* __restrict__ lists,
    const float* __restrict__ wlists, const int* __restrict__ counts,
    const int* __restrict__ hbase_g, const int2* __restrict__ tableR,
    const int* __restrict__ tns, int tidx, float* __restrict__ out)
{
  if ((int)blockIdx.x >= tns[tidx]) return;
  int2 ent = tableR[blockIdx.x];
  int li = ent.x, m0 = ent.y;
  int cnt = counts[li];
  int hbase = hbase_g[li];
  int e = li & 31;
  int n0 = blockIdx.y * 128;
  const unsigned short* w2 = w2rT + (size_t)e * DM * FD;

  __shared__ __align__(16) unsigned short As[64 * 64];
  __shared__ __align__(16) unsigned short Bs[128 * 64];

  int tid = threadIdx.x;
  int lane = tid & 63, wave = tid >> 6;
  int wr = (wave >> 1) * 32, wc = (wave & 1) * 64;
  int l15 = lane & 15, l4 = lane >> 4;

  f32x4 zz = {0.f, 0.f, 0.f, 0.f};
  f32x4 acc[2][4];
  #pragma unroll
  for (int i = 0; i < 2; ++i)
    #pragma unroll
    for (int j = 0; j < 4; ++j) acc[i][j] = zz;

  int g = lane & 7, lr = lane >> 3;
  const unsigned short* agsrc[2];  unsigned short* aldst[2];
  #pragma unroll
  for (int p = 0; p < 2; ++p) {
    int arow = wave * 16 + p * 8 + lr;
    agsrc[p] = hbuf + (size_t)(hbase + m0 + arow) * FD + ((g ^ (arow & 7)) << 3);
    aldst[p] = As + (wave * 16 + p * 8) * 64;
  }
  const unsigned short* bgsrc[4];  unsigned short* bldst[4];
  #pragma unroll
  for (int p = 0; p < 4; ++p) {
    int brow = wave * 32 + p * 8 + lr;
    bgsrc[p] = w2 + (size_t)(n0 + brow) * FD + ((g ^ (brow & 7)) << 3);
    bldst[p] = Bs + (wave * 32 + p * 8) * 64;
  }

  for (int k0 = 0; k0 < FD; k0 += 64) {
    #pragma unroll
    for (int p = 0; p < 2; ++p) gld16(agsrc[p] + k0, aldst[p]);
    #pragma unroll
    for (int p = 0; p < 4; ++p) gld16(bgsrc[p] + k0, bldst[p]);
    __syncthreads();
    #pragma unroll
    for (int kk = 0; kk < 2; ++kk) {
      bf16x8 af[2], bfr[4];
      #pragma unroll
      for (int mi = 0; mi < 2; ++mi) af[mi] = fragld(As, wr + mi * 16 + l15, kk * 4 + l4);
      #pragma unroll
      for (int ni = 0; ni < 4; ++ni) bfr[ni] = fragld(Bs, wc + ni * 16 + l15, kk * 4 + l4);
      #pragma unroll
      for (int mi = 0; mi < 2; ++mi)
        #pragma unroll
        for (int ni = 0; ni < 4; ++ni) acc[mi][ni] = mfma16(af[mi], bfr[ni], acc[mi][ni]);
    }
    __syncthreads();
  }

  int rb4 = l4 * 4;
  #pragma unroll
  for (int mi = 0; mi < 2; ++mi) {
    #pragma unroll
    for (int rg = 0; rg < 4; ++rg) {
      int gi = m0 + wr + mi * 16 + rb4 + rg;
      if (gi < cnt) {
        int tok = lists[(size_t)li * NTOK + gi];
        float wgt = wlists[(size_t)li * NTOK + gi];
        #pragma unroll
        for (int ni = 0; ni < 4; ++ni) {
          int ncol = n0 + wc + ni * 16 + l15;
          float v = (acc[mi][ni][rg] + rb2[(size_t)e * DM + ncol]) * wgt;
          out[(size_t)tok * DM + ncol] += v;
        }
      }
    }
  }
}

// ---------------- launch ----------------
extern "C" void kernel_launch(void* const* d_in, const int* in_sizes, int n_in,
                              void* d_out, int out_size, void* d_ws, size_t ws_size,
                              hipStream_t stream) {
  const float* x   = (const float*)d_in[0];
  const float* sw1 = (const float*)d_in[1];
  const float* sb1 = (const float*)d_in[2];
  const float* sw2 = (const float*)d_in[3];
  const float* sb2 = (const float*)d_in[4];
  const float* rw1 = (const float*)d_in[5];
  const float* rb1 = (const float*)d_in[6];
  const float* rw2 = (const float*)d_in[7];
  const float* rb2 = (const float*)d_in[8];
  const float* gw  = (const float*)d_in[9];
  const float* gb  = (const float*)d_in[10];
  float* out = (float*)d_out;
  char* ws = (char*)d_ws;

  if (ws_size >= WS_NEW) {
    float* logits  = (float*)(ws + L_LOGITS);
    int* counts    = (int*)(ws + L_COUNTS);
    int* hbase_g   = (int*)(ws + L_HBASE);
    int2* tableA   = (int2*)(ws + L_TABA);
    int2* tableR0  = (int2*)(ws + L_TABR0);
    int2* tableR1  = (int2*)(ws + L_TABR1);
    int* tns       = (int*)(ws + L_TNS);
    int* lists     = (int*)(ws + L_LISTS);
    float* wlists  = (float*)(ws + L_WLIST);
    unsigned short* hbuf = (unsigned short*)(ws + L_HBUF);
    unsigned short* xbf  = (unsigned short*)(ws + L_XBF);
    unsigned short* w1T  = (unsigned short*)(ws + L_W1T);
    unsigned short* w2sT = (unsigned short*)(ws + L_W2ST);
    unsigned short* w2rT = (unsigned short*)(ws + L_W2RT);

    hipMemsetAsync(counts, 0, 64 * sizeof(int), stream);
    gate_v3<<<dim3(NTOK / 8), 256, 0, stream>>>(x, gw, gb, logits, xbf);
    topk_kernel<<<dim3(NTOK / 256), 256, 0, stream>>>(logits, counts, lists, wlists);
    scan_v4<<<1, 128, 0, stream>>>(counts, hbase_g, tableA, tableR0, tableR1, tns);
    conv_w1_v2<<<dim3(34, 80, 6), 256, 0, stream>>>(sw1, rw1, w1T);
    conv_w2_v2<<<dim3(33, 12, 80), 256, 0, stream>>>(sw2, rw2, w2sT, w2rT);
    ffn1_v4<<<dim3(192, 3), 256, 0, stream>>>(xbf, w1T, sb1, rb1, lists, counts,
                                              hbase_g, tableA, tns, hbuf);
    ffn2_shared_v2<<<dim3(32, 40), 256, 0, stream>>>(hbuf, w2sT, sb2, out);
    ffn2_routed_v2<<<dim3(128, 40), 256, 0, stream>>>(hbuf, w2rT, rb2, lists, wlists,
                                                      counts, hbase_g, tableR0, tns, 1, out);
    ffn2_routed_v2<<<dim3(128, 40), 256, 0, stream>>>(hbuf, w2rT, rb2, lists, wlists,
                                                      counts, hbase_g, tableR1, tns, 2, out);
    return;
  }

  // ---------------- fallback: round-1 proven path ----------------
  if (ws_size < WS_OLD) return;
  float* logits   = (float*)(ws + OFF_LOGITS);
  int* counts     = (int*)(ws + OFF_COUNTS);
  int* seg_count  = (int*)(ws + OFF_SEGC);
  int* seg_hbase  = (int*)(ws + OFF_SEGB);
  int2* tableA    = (int2*)(ws + OFF_TABA);
  int2* tableR0   = (int2*)(ws + OFF_TABR0);
  int2* tableR1   = (int2*)(ws + OFF_TABR1);
  int* tns        = (int*)(ws + OFF_TNS);
  int* lists      = (int*)(ws + OFF_LISTS);
  float* wlists   = (float*)(ws + OFF_WLISTS);
  unsigned short* hbuf = (unsigned short*)(ws + OFF_HBUF);

  hipMemsetAsync(counts, 0, 64 * sizeof(int), stream);
  gate_logits_kernel<<<dim3(NTOK / 16), 256, 0, stream>>>(x, gw, gb, logits, (unsigned short*)0);
  topk_kernel<<<dim3(NTOK / 256), 256, 0, stream>>>(logits, counts, lists, wlists);
  scan_kernel<<<1, 1, 0, stream>>>(counts, seg_count, seg_hbase, tableA, tableR0, tableR1, tns);
  ffn1_kernel<<<dim3(384, 6), 256, 0, stream>>>(x, sw1, sb1, rw1, rb1, lists,
                                                seg_count, seg_hbase, tableA, tns, hbuf);
  ffn2_shared_kernel<<<dim3(64, 80), 256, 0, stream>>>(hbuf, sw2, sb2, out);
  ffn2_routed_kernel<<<dim3(128, 80), 256, 0, stream>>>(hbuf, rw2, rb2, lists, wlists,
                                                        counts, seg_hbase, tableR0, tns, 1, out);
  ffn2_routed_kernel<<<dim3(128, 80), 256, 0, stream>>>(hbuf, rw2, rb2, lists, wlists,
                                                        counts, seg_hbase, tableR1, tns, 2, out);
}